// Round 4
// baseline (826.723 us; speedup 1.0000x reference)
//
#include <hip/hip_runtime.h>
#include <stdint.h>

// ---------------------------------------------------------------------------
// FakeNewsModel: 3-layer GraphSAGE (mean agg), N=50000, E=1.6M, width 64.
// Round 7: fix the LDS-doubling bug found in round-6 counters. Both template
// instantiations of project_body declared their own __shared__ red[] ->
// 66560 B/block -> 2 blocks/CU -> 31% occupancy cap (latency-bound at 150us,
// VALUBusy 16%). Now the kernel declares ONE shared buffer and passes it in:
// 33280 B -> 4 blocks/CU -> 32 waves/CU; __launch_bounds__(512,8) pins
// VGPR<=64 (currently 52). k_layer: gather unrolled 4->8 (8 loads in flight,
// half the dependent-chain depth). Everything else identical.
//   k_detect  -> flags[0]=floats-are-bf16?, flags[1]=ints-are-int64?
//   CSR build -> memset(cnt), k_deg, k_scan1/2/3, k_scatter
//   k_project -> x0 = concat(xc@Wp+bp, xs@Ws+bs)  (fp32 h-table)
//   k_layer x3 -> relu(mean-agg@Wl + bl + x@Wr); layer 3 fuses [64,2] head.
// ---------------------------------------------------------------------------

typedef __attribute__((ext_vector_type(8))) unsigned short u16x8;
typedef __attribute__((ext_vector_type(4))) float f32x4;

static __device__ __forceinline__ float bf2f(unsigned short u) {
  union { unsigned int i; float f; } v;
  v.i = ((unsigned int)u) << 16;
  return v.f;
}

static __device__ __forceinline__ unsigned short f2bf(float f) {
  union { float f; unsigned int i; } v;
  v.f = f;
  unsigned int u = v.i;
  unsigned int r = (u + 0x7FFFu + ((u >> 16) & 1u)) >> 16;  // RNE
  return (unsigned short)r;
}

template <bool BF>
static __device__ __forceinline__ float ldf(const void* p, long long i) {
  if (BF) return bf2f(((const unsigned short*)p)[i]);
  return ((const float*)p)[i];
}

// 8 consecutive floats starting at element idx (16B-aligned in bf16 world).
template <bool BF>
static __device__ __forceinline__ void load8(const void* p, long long idx,
                                             float* out) {
  if (BF) {
    u16x8 v = *(const u16x8*)((const unsigned short*)p + idx);
#pragma unroll
    for (int j = 0; j < 8; ++j) out[j] = bf2f(v[j]);
  } else {
    f32x4 a = *(const f32x4*)((const float*)p + idx);
    f32x4 b = *(const f32x4*)((const float*)p + idx + 4);
#pragma unroll
    for (int j = 0; j < 4; ++j) {
      out[j] = a[j];
      out[4 + j] = b[j];
    }
  }
}

// 8 consecutive W values: row `row`, columns [8*q, 8*q+8) of a [K,32] matrix.
// row and q are wave-uniform -> compiler emits scalar (s_load) loads.
template <bool BF>
static __device__ __forceinline__ void loadw8q(const void* p, int row, int q,
                                               float* wv) {
  if (BF) {
    const unsigned int* d = (const unsigned int*)p + row * 16 + q * 4;
#pragma unroll
    for (int t = 0; t < 4; ++t) {
      unsigned int u = d[t];
      union { unsigned int i; float f; } c0, c1;
      c0.i = u << 16;
      c1.i = u & 0xFFFF0000u;
      wv[2 * t + 0] = c0.f;
      wv[2 * t + 1] = c1.f;
    }
  } else {
    const float* d = (const float*)p + row * 32 + q * 8;
#pragma unroll
    for (int t = 0; t < 8; ++t) wv[t] = d[t];
  }
}

static __device__ __forceinline__ int clampN(int v, int N) {
  return v < 0 ? 0 : (v >= N ? N - 1 : v);
}

// ---------------- dtype detection ----------------
__global__ void k_detect(const void* Wp, const int* ei, int* flags) {
  if (threadIdx.x == 0 && blockIdx.x == 0) {
    const unsigned short* w = (const unsigned short*)Wp;
    int bf = 1;
    for (int i = 0; i < 64; ++i) {
      float v = fabsf(bf2f(w[i]));
      if (!(v < 1.0f)) bf = 0;  // catches NaN too
    }
    flags[0] = bf;
    int i64 = 1;
    for (int i = 0; i < 32; ++i)
      if (ei[2 * i + 1] != 0) i64 = 0;
    flags[1] = i64;
  }
}

static __device__ __forceinline__ int edge_src(const int* ei, int e, int E,
                                               int i64) {
  return i64 ? ei[2 * (long long)e] : ei[e];
}
static __device__ __forceinline__ int edge_dst(const int* ei, int e, int E,
                                               int i64) {
  return i64 ? ei[2 * ((long long)E + e)] : ei[(long long)E + e];
}

// ---------------- CSR build ----------------

__global__ __launch_bounds__(256) void k_deg(const int* __restrict__ ei, int E,
                                             int N, int* __restrict__ cnt,
                                             const int* __restrict__ flags) {
  int e = blockIdx.x * 256 + threadIdx.x;
  if (e < E) {
    int d = clampN(edge_dst(ei, e, E, flags[1]), N);
    atomicAdd(&cnt[d], 1);
  }
}

__global__ __launch_bounds__(256) void k_scan1(const int* __restrict__ cnt,
                                               int* __restrict__ rowptr,
                                               int* __restrict__ bsum, int N) {
  __shared__ int sh[256];
  int t = threadIdx.x;
  int base = blockIdx.x * 1024 + t * 4;
  int v0 = 0, v1 = 0, v2 = 0, v3 = 0;
  if (base + 0 < N) v0 = cnt[base + 0];
  if (base + 1 < N) v1 = cnt[base + 1];
  if (base + 2 < N) v2 = cnt[base + 2];
  if (base + 3 < N) v3 = cnt[base + 3];
  int s = v0 + v1 + v2 + v3;
  sh[t] = s;
  __syncthreads();
  int acc = s;
  for (int off = 1; off < 256; off <<= 1) {
    int x = 0;
    if (t >= off) x = sh[t - off];
    __syncthreads();
    acc += x;
    sh[t] = acc;
    __syncthreads();
  }
  int run = acc - s;
  if (base + 0 < N) rowptr[base + 0] = run;
  run += v0;
  if (base + 1 < N) rowptr[base + 1] = run;
  run += v1;
  if (base + 2 < N) rowptr[base + 2] = run;
  run += v2;
  if (base + 3 < N) rowptr[base + 3] = run;
  run += v3;
  if (t == 255) bsum[blockIdx.x] = acc;
}

__global__ void k_scan2(int* __restrict__ bsum, int nb,
                        int* __restrict__ rowptr, int N) {
  if (threadIdx.x == 0 && blockIdx.x == 0) {
    int run = 0;
    for (int i = 0; i < nb; ++i) {
      int v = bsum[i];
      bsum[i] = run;
      run += v;
    }
    rowptr[N] = run;
  }
}

__global__ __launch_bounds__(256) void k_scan3(int* __restrict__ rowptr,
                                               int* __restrict__ cursor,
                                               const int* __restrict__ bsum,
                                               int N) {
  int i = blockIdx.x * 256 + threadIdx.x;
  if (i < N) {
    int v = rowptr[i] + bsum[i >> 10];
    rowptr[i] = v;
    cursor[i] = v;
  }
}

__global__ __launch_bounds__(256) void k_scatter(const int* __restrict__ ei,
                                                 int E, int N,
                                                 int* __restrict__ cursor,
                                                 int* __restrict__ colbuf,
                                                 const int* __restrict__ flags) {
  int e = blockIdx.x * 256 + threadIdx.x;
  if (e < E) {
    int i64 = flags[1];
    int s = clampN(edge_src(ei, e, E, i64), N);
    int d = clampN(edge_dst(ei, e, E, i64), N);
    int p = atomicAdd(&cursor[d], 1);
    if (p >= 0 && p < E) colbuf[p] = s;
  }
}

// ---------------- projection (v6: K-split waves, single shared buffer) ------
// Block = 512 threads = 8 waves over 64 nodes. Wave w -> (q = w&3, h = w>>2):
// computes output columns [8q, 8q+8) of content AND style over K-half h.
// Column quarter and K-half are wave-uniform -> W loads are scalar (s_load).
// Partials meet in LDS red[2][64][65] (stride 65 -> conflict-free); the
// buffer is declared ONCE in the kernel (round-6 bug: each template
// instantiation had its own -> 2x LDS -> occupancy capped at 2 blocks/CU).
template <bool BF>
static __device__ void project_body(const void* __restrict__ xc,
                                    const void* __restrict__ xs,
                                    const void* __restrict__ Wp,
                                    const void* __restrict__ bp,
                                    const void* __restrict__ Ws,
                                    const void* __restrict__ bs,
                                    float* __restrict__ h0, int N,
                                    float* __restrict__ red) {
  int tid = (int)threadIdx.x;
  int w = __builtin_amdgcn_readfirstlane(tid >> 6);  // 0..7
  int q = w & 3;   // out-quarter
  int h = w >> 2;  // K-half
  int lane = tid & 63;
  int node = (int)blockIdx.x * 64 + lane;
  int nclamp = node < N ? node : (N - 1);

  float accc[8], accs[8];
#pragma unroll
  for (int r = 0; r < 8; ++r) {
    accc[r] = 0.f;
    accs[r] = 0.f;
  }

  // ---- content slice: x[384h .. 384h+384) dot Wp[rows, 8q..8q+8) ----
  {
    long long xoff = (long long)nclamp * 768 + h * 384;
    int rbase = h * 384;
    float a0[8], a1[8], n0[8], n1[8];
    load8<BF>(xc, xoff + 0, a0);
    load8<BF>(xc, xoff + 8, a1);
#pragma unroll 1
    for (int k = 0; k < 384; k += 16) {
      int k2 = (k + 16 < 384) ? (k + 16) : 0;  // always-valid prefetch addr
      load8<BF>(xc, xoff + k2, n0);
      load8<BF>(xc, xoff + k2 + 8, n1);
#pragma unroll
      for (int j = 0; j < 8; ++j) {
        float wv[8];
        loadw8q<BF>(Wp, rbase + k + j, q, wv);
#pragma unroll
        for (int r = 0; r < 8; ++r) accc[r] += a0[j] * wv[r];
      }
#pragma unroll
      for (int j = 0; j < 8; ++j) {
        float wv[8];
        loadw8q<BF>(Wp, rbase + k + 8 + j, q, wv);
#pragma unroll
        for (int r = 0; r < 8; ++r) accc[r] += a1[j] * wv[r];
      }
#pragma unroll
      for (int j = 0; j < 8; ++j) {
        a0[j] = n0[j];
        a1[j] = n1[j];
      }
    }
  }

  // ---- style slice: x[64h .. 64h+64) dot Ws[rows, 8q..8q+8) ----
  {
    long long soff = (long long)nclamp * 128 + h * 64;
    int rbase = h * 64;
    float a0[8], a1[8], n0[8], n1[8];
    load8<BF>(xs, soff + 0, a0);
    load8<BF>(xs, soff + 8, a1);
#pragma unroll 1
    for (int k = 0; k < 64; k += 16) {
      int k2 = (k + 16 < 64) ? (k + 16) : 0;
      load8<BF>(xs, soff + k2, n0);
      load8<BF>(xs, soff + k2 + 8, n1);
#pragma unroll
      for (int j = 0; j < 8; ++j) {
        float wv[8];
        loadw8q<BF>(Ws, rbase + k + j, q, wv);
#pragma unroll
        for (int r = 0; r < 8; ++r) accs[r] += a0[j] * wv[r];
      }
#pragma unroll
      for (int j = 0; j < 8; ++j) {
        float wv[8];
        loadw8q<BF>(Ws, rbase + k + 8 + j, q, wv);
#pragma unroll
        for (int r = 0; r < 8; ++r) accs[r] += a1[j] * wv[r];
      }
#pragma unroll
      for (int j = 0; j < 8; ++j) {
        a0[j] = n0[j];
        a1[j] = n1[j];
      }
    }
  }

  // ---- write partials to LDS: red[(h*64+lane)*65 + out] ----
  {
    float* row = red + (h * 64 + lane) * 65;
#pragma unroll
    for (int r = 0; r < 8; ++r) {
      row[8 * q + r] = accc[r];
      row[32 + 8 * q + r] = accs[r];
    }
  }
  __syncthreads();

  // ---- combine halves + bias, coalesced store ----
  {
    int n2 = tid >> 3;        // 0..63 (node within block)
    int oc = (tid & 7) * 8;   // 0,8,...,56
    int gnode = (int)blockIdx.x * 64 + n2;
    if (gnode < N) {
      float v[8];
#pragma unroll
      for (int i = 0; i < 8; ++i) {
        int out = oc + i;
        float b = (out < 32) ? ldf<BF>(bp, out) : ldf<BF>(bs, out - 32);
        v[i] = red[n2 * 65 + out] + red[(64 + n2) * 65 + out] + b;
      }
      float* orow = h0 + (long long)gnode * 64 + oc;
      f32x4 v0 = {v[0], v[1], v[2], v[3]};
      f32x4 v1 = {v[4], v[5], v[6], v[7]};
      *(f32x4*)orow = v0;
      *(f32x4*)(orow + 4) = v1;
    }
  }
}

__global__ __launch_bounds__(512, 8) void k_project(
    const void* __restrict__ xc, const void* __restrict__ xs,
    const void* __restrict__ Wp, const void* __restrict__ bp,
    const void* __restrict__ Ws, const void* __restrict__ bs,
    float* __restrict__ h0, int N, const int* __restrict__ flags) {
  __shared__ float red[2 * 64 * 65];  // single allocation for both paths
  if (flags[0])
    project_body<true>(xc, xs, Wp, bp, Ws, bs, h0, N, red);
  else
    project_body<false>(xc, xs, Wp, bp, Ws, bs, h0, N, red);
}

// ---------------- SAGE layer ----------------
template <bool BF>
static __device__ void layer_body(const float* __restrict__ hin,
                                  const int* __restrict__ rowptr,
                                  const int* __restrict__ colbuf,
                                  const void* Wl, const void* bl,
                                  const void* Wr, float* __restrict__ hout,
                                  int N, int last, const void* Wo,
                                  const void* bo, void* outp) {
  int node = (int)((blockIdx.x * blockDim.x + threadIdx.x) >> 6);
  int lane = (int)(threadIdx.x & 63);
  if (node >= N) return;
  int rs = rowptr[node], re = rowptr[node + 1];
  float xself = hin[(long long)node * 64 + lane];
  float agg0 = 0.f, agg1 = 0.f, agg2 = 0.f, agg3 = 0.f;
  float agg4 = 0.f, agg5 = 0.f, agg6 = 0.f, agg7 = 0.f;
  for (int cb = rs; cb < re; cb += 64) {
    int sidx = 0;
    if (cb + lane < re) sidx = clampN(colbuf[cb + lane], N);
    int c = re - cb;
    if (c > 64) c = 64;
    int t = 0;
    for (; t + 8 <= c; t += 8) {
      int s0 = __builtin_amdgcn_readlane(sidx, t + 0);
      int s1 = __builtin_amdgcn_readlane(sidx, t + 1);
      int s2 = __builtin_amdgcn_readlane(sidx, t + 2);
      int s3 = __builtin_amdgcn_readlane(sidx, t + 3);
      int s4 = __builtin_amdgcn_readlane(sidx, t + 4);
      int s5 = __builtin_amdgcn_readlane(sidx, t + 5);
      int s6 = __builtin_amdgcn_readlane(sidx, t + 6);
      int s7 = __builtin_amdgcn_readlane(sidx, t + 7);
      float v0 = hin[(long long)s0 * 64 + lane];
      float v1 = hin[(long long)s1 * 64 + lane];
      float v2 = hin[(long long)s2 * 64 + lane];
      float v3 = hin[(long long)s3 * 64 + lane];
      float v4 = hin[(long long)s4 * 64 + lane];
      float v5 = hin[(long long)s5 * 64 + lane];
      float v6 = hin[(long long)s6 * 64 + lane];
      float v7 = hin[(long long)s7 * 64 + lane];
      agg0 += v0;
      agg1 += v1;
      agg2 += v2;
      agg3 += v3;
      agg4 += v4;
      agg5 += v5;
      agg6 += v6;
      agg7 += v7;
    }
    for (; t < c; ++t) {
      int s = __builtin_amdgcn_readlane(sidx, t);
      agg0 += hin[(long long)s * 64 + lane];
    }
  }
  float agg = ((agg0 + agg1) + (agg2 + agg3)) + ((agg4 + agg5) + (agg6 + agg7));
  int deg = re - rs;
  if (deg > 0) agg *= (1.f / (float)deg);

  float o = ldf<BF>(bl, lane);
#pragma unroll 8
  for (int d = 0; d < 64; ++d) {
    float ad = __uint_as_float(
        __builtin_amdgcn_readlane(__float_as_uint(agg), d));
    float xd = __uint_as_float(
        __builtin_amdgcn_readlane(__float_as_uint(xself), d));
    o += ad * ldf<BF>(Wl, d * 64 + lane);
    o += xd * ldf<BF>(Wr, d * 64 + lane);
  }
  o = fmaxf(o, 0.f);

  if (!last) {
    hout[(long long)node * 64 + lane] = o;
  } else {
    float c0 = o * ldf<BF>(Wo, lane * 2 + 0);
    float c1 = o * ldf<BF>(Wo, lane * 2 + 1);
    for (int off = 32; off > 0; off >>= 1) {
      c0 += __shfl_xor(c0, off, 64);
      c1 += __shfl_xor(c1, off, 64);
    }
    if (lane == 0) {
      float r0 = c0 + ldf<BF>(bo, 0);
      float r1 = c1 + ldf<BF>(bo, 1);
      if (BF) {
        unsigned short* o16 = (unsigned short*)outp;
        o16[(long long)node * 2 + 0] = f2bf(r0);
        o16[(long long)node * 2 + 1] = f2bf(r1);
      } else {
        float* o32 = (float*)outp;
        o32[(long long)node * 2 + 0] = r0;
        o32[(long long)node * 2 + 1] = r1;
      }
    }
  }
}

__global__ __launch_bounds__(256) void k_layer(
    const float* hin, const int* rowptr, const int* colbuf, const void* Wl,
    const void* bl, const void* Wr, float* hout, int N, int last,
    const void* Wo, const void* bo, void* outp, const int* __restrict__ flags) {
  if (flags[0])
    layer_body<true>(hin, rowptr, colbuf, Wl, bl, Wr, hout, N, last, Wo, bo,
                     outp);
  else
    layer_body<false>(hin, rowptr, colbuf, Wl, bl, Wr, hout, N, last, Wo, bo,
                      outp);
}

// ---------------- host ----------------

extern "C" void kernel_launch(void* const* d_in, const int* in_sizes, int n_in,
                              void* d_out, int out_size, void* d_ws,
                              size_t ws_size, hipStream_t stream) {
  const void* xc = d_in[0];
  const void* xs = d_in[1];
  const int* ei = (const int*)d_in[2];
  const void* Wp = d_in[4];
  const void* bp = d_in[5];
  const void* Ws = d_in[6];
  const void* bs = d_in[7];
  const void* Wl1 = d_in[8];
  const void* bl1 = d_in[9];
  const void* Wr1 = d_in[10];
  const void* Wl2 = d_in[11];
  const void* bl2 = d_in[12];
  const void* Wr2 = d_in[13];
  const void* Wl3 = d_in[14];
  const void* bl3 = d_in[15];
  const void* Wr3 = d_in[16];
  const void* Wo = d_in[17];
  const void* bo = d_in[18];

  int N = out_size / 2;   // output is [N, 2]
  int E = in_sizes[3];    // edge_type has E elements

  char* ws = (char*)d_ws;
  size_t off = 0;
  auto alloc = [&](size_t bytes) {
    char* p = ws + off;
    off += (bytes + 255) & ~(size_t)255;
    return p;
  };
  int* colbuf = (int*)alloc((size_t)E * 4);
  int* cnt = (int*)alloc((size_t)N * 4);
  int* rowptr = (int*)alloc((size_t)(N + 1) * 4);
  int* cursor = (int*)alloc((size_t)N * 4);
  int* bsum = (int*)alloc(4096);
  int* flags = (int*)alloc(256);
  float* h0 = (float*)alloc((size_t)N * 64 * 4);
  float* h1 = (float*)alloc((size_t)N * 64 * 4);
  (void)ws_size;
  (void)n_in;

  k_detect<<<1, 64, 0, stream>>>(Wp, ei, flags);

  hipMemsetAsync(cnt, 0, (size_t)N * 4, stream);
  int eb = (E + 255) / 256;
  k_deg<<<eb, 256, 0, stream>>>(ei, E, N, cnt, flags);
  int sb = (N + 1023) / 1024;
  k_scan1<<<sb, 256, 0, stream>>>(cnt, rowptr, bsum, N);
  k_scan2<<<1, 64, 0, stream>>>(bsum, sb, rowptr, N);
  k_scan3<<<(N + 255) / 256, 256, 0, stream>>>(rowptr, cursor, bsum, N);
  k_scatter<<<eb, 256, 0, stream>>>(ei, E, N, cursor, colbuf, flags);

  int pb = (N + 63) / 64;  // 64 nodes per 512-thread block (8 waves, K-split)
  k_project<<<pb, 512, 0, stream>>>(xc, xs, Wp, bp, Ws, bs, h0, N, flags);

  int nb4 = (N + 3) / 4;  // 4 waves (nodes) per 256-thread block
  k_layer<<<nb4, 256, 0, stream>>>(h0, rowptr, colbuf, Wl1, bl1, Wr1, h1, N, 0,
                                   nullptr, nullptr, nullptr, flags);
  k_layer<<<nb4, 256, 0, stream>>>(h1, rowptr, colbuf, Wl2, bl2, Wr2, h0, N, 0,
                                   nullptr, nullptr, nullptr, flags);
  k_layer<<<nb4, 256, 0, stream>>>(h0, rowptr, colbuf, Wl3, bl3, Wr3, h1, N, 1,
                                   Wo, bo, d_out, flags);
}

// Round 5
// 786.867 us; speedup vs baseline: 1.0507x; 1.0507x over previous
//
#include <hip/hip_runtime.h>
#include <stdint.h>

// ---------------------------------------------------------------------------
// FakeNewsModel: 3-layer GraphSAGE (mean agg), N=50000, E=1.6M, width 64.
// Round 8: k_project v7 — LDS-staged coalesced x tiles (the §5 GEMM shape).
// Round-7 post-mortem: __launch_bounds__(512,8) forced VGPR 52->32 -> spills
// (WRITE_SIZE +6.3MB) and occupancy is grid-capped at 3.05 blocks/CU anyway.
// The real bottleneck: every FMA chunk depended on its own 64-scattered-line
// load; at ~3 waves/SIMD nothing hides ~900cyc latency (VALUBusy stuck 13%).
// v7: 256-thr block = 4 waves = 64 nodes. 14 K-tiles of 64 (12 content +
// 2 style) staged into xt[2][64][65] f32 LDS (stride 65 -> 2-way bank = free)
// with coalesced 128B/node loads, double-buffered, T14 split (load regs
// early, ds_write after compute) so HBM latency hides under a full tile of
// compute per wave. Wave w owns content cols [8w,8w+8) + style [8w,8w+8) for
// ALL K -> no cross-wave reduction. W loads stay wave-uniform scalar s_load.
// No min-waves bound. k_layer unchanged (round-4 unroll-8 version).
//   k_detect  -> flags[0]=floats-are-bf16?, flags[1]=ints-are-int64?
//   CSR build -> memset(cnt), k_deg, k_scan1/2/3, k_scatter
//   k_project -> x0 = concat(xc@Wp+bp, xs@Ws+bs)  (fp32 h-table)
//   k_layer x3 -> relu(mean-agg@Wl + bl + x@Wr); layer 3 fuses [64,2] head.
// ---------------------------------------------------------------------------

typedef __attribute__((ext_vector_type(8))) unsigned short u16x8;
typedef __attribute__((ext_vector_type(4))) float f32x4;

static __device__ __forceinline__ float bf2f(unsigned short u) {
  union { unsigned int i; float f; } v;
  v.i = ((unsigned int)u) << 16;
  return v.f;
}

static __device__ __forceinline__ unsigned short f2bf(float f) {
  union { float f; unsigned int i; } v;
  v.f = f;
  unsigned int u = v.i;
  unsigned int r = (u + 0x7FFFu + ((u >> 16) & 1u)) >> 16;  // RNE
  return (unsigned short)r;
}

template <bool BF>
static __device__ __forceinline__ float ldf(const void* p, long long i) {
  if (BF) return bf2f(((const unsigned short*)p)[i]);
  return ((const float*)p)[i];
}

// 8 consecutive W values: row `row`, columns [8*q, 8*q+8) of a [K,32] matrix.
// row and q are wave-uniform -> compiler emits scalar (s_load) loads.
template <bool BF>
static __device__ __forceinline__ void loadw8q(const void* p, int row, int q,
                                               float* wv) {
  if (BF) {
    const unsigned int* d = (const unsigned int*)p + row * 16 + q * 4;
#pragma unroll
    for (int t = 0; t < 4; ++t) {
      unsigned int u = d[t];
      union { unsigned int i; float f; } c0, c1;
      c0.i = u << 16;
      c1.i = u & 0xFFFF0000u;
      wv[2 * t + 0] = c0.f;
      wv[2 * t + 1] = c1.f;
    }
  } else {
    const float* d = (const float*)p + row * 32 + q * 8;
#pragma unroll
    for (int t = 0; t < 8; ++t) wv[t] = d[t];
  }
}

static __device__ __forceinline__ int clampN(int v, int N) {
  return v < 0 ? 0 : (v >= N ? N - 1 : v);
}

// ---------------- dtype detection ----------------
__global__ void k_detect(const void* Wp, const int* ei, int* flags) {
  if (threadIdx.x == 0 && blockIdx.x == 0) {
    const unsigned short* w = (const unsigned short*)Wp;
    int bf = 1;
    for (int i = 0; i < 64; ++i) {
      float v = fabsf(bf2f(w[i]));
      if (!(v < 1.0f)) bf = 0;  // catches NaN too
    }
    flags[0] = bf;
    int i64 = 1;
    for (int i = 0; i < 32; ++i)
      if (ei[2 * i + 1] != 0) i64 = 0;
    flags[1] = i64;
  }
}

static __device__ __forceinline__ int edge_src(const int* ei, int e, int E,
                                               int i64) {
  return i64 ? ei[2 * (long long)e] : ei[e];
}
static __device__ __forceinline__ int edge_dst(const int* ei, int e, int E,
                                               int i64) {
  return i64 ? ei[2 * ((long long)E + e)] : ei[(long long)E + e];
}

// ---------------- CSR build ----------------

__global__ __launch_bounds__(256) void k_deg(const int* __restrict__ ei, int E,
                                             int N, int* __restrict__ cnt,
                                             const int* __restrict__ flags) {
  int e = blockIdx.x * 256 + threadIdx.x;
  if (e < E) {
    int d = clampN(edge_dst(ei, e, E, flags[1]), N);
    atomicAdd(&cnt[d], 1);
  }
}

__global__ __launch_bounds__(256) void k_scan1(const int* __restrict__ cnt,
                                               int* __restrict__ rowptr,
                                               int* __restrict__ bsum, int N) {
  __shared__ int sh[256];
  int t = threadIdx.x;
  int base = blockIdx.x * 1024 + t * 4;
  int v0 = 0, v1 = 0, v2 = 0, v3 = 0;
  if (base + 0 < N) v0 = cnt[base + 0];
  if (base + 1 < N) v1 = cnt[base + 1];
  if (base + 2 < N) v2 = cnt[base + 2];
  if (base + 3 < N) v3 = cnt[base + 3];
  int s = v0 + v1 + v2 + v3;
  sh[t] = s;
  __syncthreads();
  int acc = s;
  for (int off = 1; off < 256; off <<= 1) {
    int x = 0;
    if (t >= off) x = sh[t - off];
    __syncthreads();
    acc += x;
    sh[t] = acc;
    __syncthreads();
  }
  int run = acc - s;
  if (base + 0 < N) rowptr[base + 0] = run;
  run += v0;
  if (base + 1 < N) rowptr[base + 1] = run;
  run += v1;
  if (base + 2 < N) rowptr[base + 2] = run;
  run += v2;
  if (base + 3 < N) rowptr[base + 3] = run;
  run += v3;
  if (t == 255) bsum[blockIdx.x] = acc;
}

__global__ void k_scan2(int* __restrict__ bsum, int nb,
                        int* __restrict__ rowptr, int N) {
  if (threadIdx.x == 0 && blockIdx.x == 0) {
    int run = 0;
    for (int i = 0; i < nb; ++i) {
      int v = bsum[i];
      bsum[i] = run;
      run += v;
    }
    rowptr[N] = run;
  }
}

__global__ __launch_bounds__(256) void k_scan3(int* __restrict__ rowptr,
                                               int* __restrict__ cursor,
                                               const int* __restrict__ bsum,
                                               int N) {
  int i = blockIdx.x * 256 + threadIdx.x;
  if (i < N) {
    int v = rowptr[i] + bsum[i >> 10];
    rowptr[i] = v;
    cursor[i] = v;
  }
}

__global__ __launch_bounds__(256) void k_scatter(const int* __restrict__ ei,
                                                 int E, int N,
                                                 int* __restrict__ cursor,
                                                 int* __restrict__ colbuf,
                                                 const int* __restrict__ flags) {
  int e = blockIdx.x * 256 + threadIdx.x;
  if (e < E) {
    int i64 = flags[1];
    int s = clampN(edge_src(ei, e, E, i64), N);
    int d = clampN(edge_dst(ei, e, E, i64), N);
    int p = atomicAdd(&cursor[d], 1);
    if (p >= 0 && p < E) colbuf[p] = s;
  }
}

// ---------------- projection (v7: LDS-staged x tiles) -----------------------
// Block = 256 threads = 4 waves = 64 nodes. 14 K-tiles of 64 elems:
// tiles 0..11 = content (K=768), 12..13 = style (K=128). Staging: thread
// (n = tid>>2, j = tid&3) loads elems [16j,16j+16) of node n's tile chunk
// (32B contiguous; per wave 16 nodes x 128B segments = coalesced) into regs,
// writes to xt[buf][n][16j..16j+16) AFTER the compute phase (T14 split).
// Compute: wave w, lane l = node l, accumulates cols [8w,8w+8) via
// xt[buf][l][k] (bank = l+k mod 32, 2-way = free) x scalar W row-chunks.
template <bool BF>
static __device__ void project_body(const void* __restrict__ xc,
                                    const void* __restrict__ xs,
                                    const void* __restrict__ Wp,
                                    const void* __restrict__ bp,
                                    const void* __restrict__ Ws,
                                    const void* __restrict__ bs,
                                    float* __restrict__ h0, int N,
                                    float* __restrict__ xt) {
  int tid = (int)threadIdx.x;
  int w = __builtin_amdgcn_readfirstlane(tid >> 6);  // 0..3 out-octant
  int lane = tid & 63;
  int node = (int)blockIdx.x * 64 + lane;

  int sn = tid >> 2;   // staging node-in-block 0..63
  int sj = tid & 3;    // staging k-chunk 0..3 (16 elems each)
  int gsn = (int)blockIdx.x * 64 + sn;
  int gsnc = gsn < N ? gsn : (N - 1);

  float c[8], s[8];
#pragma unroll
  for (int r = 0; r < 8; ++r) {
    c[r] = 0.f;
    s[r] = 0.f;
  }

  // staging registers (kept packed for BF so the vmcnt wait lands at the
  // ds_write, not before compute)
  u16x8 pr0 = {}, pr1 = {};
  f32x4 pf0 = {}, pf1 = {}, pf2 = {}, pf3 = {};

  auto stage_load = [&](int t) {
    long long idx;
    const void* src;
    if (t < 12) {
      src = xc;
      idx = (long long)gsnc * 768 + t * 64 + 16 * sj;
    } else {
      src = xs;
      idx = (long long)gsnc * 128 + (t - 12) * 64 + 16 * sj;
    }
    if (BF) {
      const unsigned short* p = (const unsigned short*)src + idx;
      pr0 = *(const u16x8*)p;
      pr1 = *(const u16x8*)(p + 8);
    } else {
      const float* p = (const float*)src + idx;
      pf0 = *(const f32x4*)(p + 0);
      pf1 = *(const f32x4*)(p + 4);
      pf2 = *(const f32x4*)(p + 8);
      pf3 = *(const f32x4*)(p + 12);
    }
  };

  auto stage_write = [&](int t) {
    float* row = xt + (t & 1) * (64 * 65) + sn * 65 + 16 * sj;
    if (BF) {
#pragma unroll
      for (int i = 0; i < 8; ++i) row[i] = bf2f(pr0[i]);
#pragma unroll
      for (int i = 0; i < 8; ++i) row[8 + i] = bf2f(pr1[i]);
    } else {
#pragma unroll
      for (int i = 0; i < 4; ++i) {
        row[i] = pf0[i];
        row[4 + i] = pf1[i];
        row[8 + i] = pf2[i];
        row[12 + i] = pf3[i];
      }
    }
  };

  // prologue: stage tile 0
  stage_load(0);
  stage_write(0);
  __syncthreads();

#pragma unroll 1
  for (int t = 0; t < 14; ++t) {
    if (t + 1 < 14) stage_load(t + 1);  // issue loads early (T14)

    const float* xrow = xt + (t & 1) * (64 * 65) + lane * 65;
    if (t < 12) {
      int rbase = t * 64;
#pragma unroll 1
      for (int k0 = 0; k0 < 64; k0 += 8) {
#pragma unroll
        for (int kk = 0; kk < 8; ++kk) {
          float xv = xrow[k0 + kk];
          float wv[8];
          loadw8q<BF>(Wp, rbase + k0 + kk, w, wv);
#pragma unroll
          for (int r = 0; r < 8; ++r) c[r] += xv * wv[r];
        }
      }
    } else {
      int rbase = (t - 12) * 64;
#pragma unroll 1
      for (int k0 = 0; k0 < 64; k0 += 8) {
#pragma unroll
        for (int kk = 0; kk < 8; ++kk) {
          float xv = xrow[k0 + kk];
          float wv[8];
          loadw8q<BF>(Ws, rbase + k0 + kk, w, wv);
#pragma unroll
          for (int r = 0; r < 8; ++r) s[r] += xv * wv[r];
        }
      }
    }

    if (t + 1 < 14) stage_write(t + 1);  // write late (waitcnt lands here)
    __syncthreads();
  }

  if (node < N) {
    float* orow = h0 + (long long)node * 64;
    f32x4 v;
#pragma unroll
    for (int r = 0; r < 4; ++r) v[r] = c[r] + ldf<BF>(bp, 8 * w + r);
    *(f32x4*)(orow + 8 * w) = v;
#pragma unroll
    for (int r = 0; r < 4; ++r) v[r] = c[4 + r] + ldf<BF>(bp, 8 * w + 4 + r);
    *(f32x4*)(orow + 8 * w + 4) = v;
#pragma unroll
    for (int r = 0; r < 4; ++r) v[r] = s[r] + ldf<BF>(bs, 8 * w + r);
    *(f32x4*)(orow + 32 + 8 * w) = v;
#pragma unroll
    for (int r = 0; r < 4; ++r) v[r] = s[4 + r] + ldf<BF>(bs, 8 * w + 4 + r);
    *(f32x4*)(orow + 32 + 8 * w + 4) = v;
  }
}

__global__ __launch_bounds__(256) void k_project(
    const void* __restrict__ xc, const void* __restrict__ xs,
    const void* __restrict__ Wp, const void* __restrict__ bp,
    const void* __restrict__ Ws, const void* __restrict__ bs,
    float* __restrict__ h0, int N, const int* __restrict__ flags) {
  __shared__ float xt[2 * 64 * 65];  // single allocation for both paths
  if (flags[0])
    project_body<true>(xc, xs, Wp, bp, Ws, bs, h0, N, xt);
  else
    project_body<false>(xc, xs, Wp, bp, Ws, bs, h0, N, xt);
}

// ---------------- SAGE layer ----------------
template <bool BF>
static __device__ void layer_body(const float* __restrict__ hin,
                                  const int* __restrict__ rowptr,
                                  const int* __restrict__ colbuf,
                                  const void* Wl, const void* bl,
                                  const void* Wr, float* __restrict__ hout,
                                  int N, int last, const void* Wo,
                                  const void* bo, void* outp) {
  int node = (int)((blockIdx.x * blockDim.x + threadIdx.x) >> 6);
  int lane = (int)(threadIdx.x & 63);
  if (node >= N) return;
  int rs = rowptr[node], re = rowptr[node + 1];
  float xself = hin[(long long)node * 64 + lane];
  float agg0 = 0.f, agg1 = 0.f, agg2 = 0.f, agg3 = 0.f;
  float agg4 = 0.f, agg5 = 0.f, agg6 = 0.f, agg7 = 0.f;
  for (int cb = rs; cb < re; cb += 64) {
    int sidx = 0;
    if (cb + lane < re) sidx = clampN(colbuf[cb + lane], N);
    int c = re - cb;
    if (c > 64) c = 64;
    int t = 0;
    for (; t + 8 <= c; t += 8) {
      int s0 = __builtin_amdgcn_readlane(sidx, t + 0);
      int s1 = __builtin_amdgcn_readlane(sidx, t + 1);
      int s2 = __builtin_amdgcn_readlane(sidx, t + 2);
      int s3 = __builtin_amdgcn_readlane(sidx, t + 3);
      int s4 = __builtin_amdgcn_readlane(sidx, t + 4);
      int s5 = __builtin_amdgcn_readlane(sidx, t + 5);
      int s6 = __builtin_amdgcn_readlane(sidx, t + 6);
      int s7 = __builtin_amdgcn_readlane(sidx, t + 7);
      float v0 = hin[(long long)s0 * 64 + lane];
      float v1 = hin[(long long)s1 * 64 + lane];
      float v2 = hin[(long long)s2 * 64 + lane];
      float v3 = hin[(long long)s3 * 64 + lane];
      float v4 = hin[(long long)s4 * 64 + lane];
      float v5 = hin[(long long)s5 * 64 + lane];
      float v6 = hin[(long long)s6 * 64 + lane];
      float v7 = hin[(long long)s7 * 64 + lane];
      agg0 += v0;
      agg1 += v1;
      agg2 += v2;
      agg3 += v3;
      agg4 += v4;
      agg5 += v5;
      agg6 += v6;
      agg7 += v7;
    }
    for (; t < c; ++t) {
      int s = __builtin_amdgcn_readlane(sidx, t);
      agg0 += hin[(long long)s * 64 + lane];
    }
  }
  float agg = ((agg0 + agg1) + (agg2 + agg3)) + ((agg4 + agg5) + (agg6 + agg7));
  int deg = re - rs;
  if (deg > 0) agg *= (1.f / (float)deg);

  float o = ldf<BF>(bl, lane);
#pragma unroll 8
  for (int d = 0; d < 64; ++d) {
    float ad = __uint_as_float(
        __builtin_amdgcn_readlane(__float_as_uint(agg), d));
    float xd = __uint_as_float(
        __builtin_amdgcn_readlane(__float_as_uint(xself), d));
    o += ad * ldf<BF>(Wl, d * 64 + lane);
    o += xd * ldf<BF>(Wr, d * 64 + lane);
  }
  o = fmaxf(o, 0.f);

  if (!last) {
    hout[(long long)node * 64 + lane] = o;
  } else {
    float c0 = o * ldf<BF>(Wo, lane * 2 + 0);
    float c1 = o * ldf<BF>(Wo, lane * 2 + 1);
    for (int off = 32; off > 0; off >>= 1) {
      c0 += __shfl_xor(c0, off, 64);
      c1 += __shfl_xor(c1, off, 64);
    }
    if (lane == 0) {
      float r0 = c0 + ldf<BF>(bo, 0);
      float r1 = c1 + ldf<BF>(bo, 1);
      if (BF) {
        unsigned short* o16 = (unsigned short*)outp;
        o16[(long long)node * 2 + 0] = f2bf(r0);
        o16[(long long)node * 2 + 1] = f2bf(r1);
      } else {
        float* o32 = (float*)outp;
        o32[(long long)node * 2 + 0] = r0;
        o32[(long long)node * 2 + 1] = r1;
      }
    }
  }
}

__global__ __launch_bounds__(256) void k_layer(
    const float* hin, const int* rowptr, const int* colbuf, const void* Wl,
    const void* bl, const void* Wr, float* hout, int N, int last,
    const void* Wo, const void* bo, void* outp, const int* __restrict__ flags) {
  if (flags[0])
    layer_body<true>(hin, rowptr, colbuf, Wl, bl, Wr, hout, N, last, Wo, bo,
                     outp);
  else
    layer_body<false>(hin, rowptr, colbuf, Wl, bl, Wr, hout, N, last, Wo, bo,
                      outp);
}

// ---------------- host ----------------

extern "C" void kernel_launch(void* const* d_in, const int* in_sizes, int n_in,
                              void* d_out, int out_size, void* d_ws,
                              size_t ws_size, hipStream_t stream) {
  const void* xc = d_in[0];
  const void* xs = d_in[1];
  const int* ei = (const int*)d_in[2];
  const void* Wp = d_in[4];
  const void* bp = d_in[5];
  const void* Ws = d_in[6];
  const void* bs = d_in[7];
  const void* Wl1 = d_in[8];
  const void* bl1 = d_in[9];
  const void* Wr1 = d_in[10];
  const void* Wl2 = d_in[11];
  const void* bl2 = d_in[12];
  const void* Wr2 = d_in[13];
  const void* Wl3 = d_in[14];
  const void* bl3 = d_in[15];
  const void* Wr3 = d_in[16];
  const void* Wo = d_in[17];
  const void* bo = d_in[18];

  int N = out_size / 2;   // output is [N, 2]
  int E = in_sizes[3];    // edge_type has E elements

  char* ws = (char*)d_ws;
  size_t off = 0;
  auto alloc = [&](size_t bytes) {
    char* p = ws + off;
    off += (bytes + 255) & ~(size_t)255;
    return p;
  };
  int* colbuf = (int*)alloc((size_t)E * 4);
  int* cnt = (int*)alloc((size_t)N * 4);
  int* rowptr = (int*)alloc((size_t)(N + 1) * 4);
  int* cursor = (int*)alloc((size_t)N * 4);
  int* bsum = (int*)alloc(4096);
  int* flags = (int*)alloc(256);
  float* h0 = (float*)alloc((size_t)N * 64 * 4);
  float* h1 = (float*)alloc((size_t)N * 64 * 4);
  (void)ws_size;
  (void)n_in;

  k_detect<<<1, 64, 0, stream>>>(Wp, ei, flags);

  hipMemsetAsync(cnt, 0, (size_t)N * 4, stream);
  int eb = (E + 255) / 256;
  k_deg<<<eb, 256, 0, stream>>>(ei, E, N, cnt, flags);
  int sb = (N + 1023) / 1024;
  k_scan1<<<sb, 256, 0, stream>>>(cnt, rowptr, bsum, N);
  k_scan2<<<1, 64, 0, stream>>>(bsum, sb, rowptr, N);
  k_scan3<<<(N + 255) / 256, 256, 0, stream>>>(rowptr, cursor, bsum, N);
  k_scatter<<<eb, 256, 0, stream>>>(ei, E, N, cursor, colbuf, flags);

  int pb = (N + 63) / 64;  // 64 nodes per 256-thread block (4 waves)
  k_project<<<pb, 256, 0, stream>>>(xc, xs, Wp, bp, Ws, bs, h0, N, flags);

  int nb4 = (N + 3) / 4;  // 4 waves (nodes) per 256-thread block
  k_layer<<<nb4, 256, 0, stream>>>(h0, rowptr, colbuf, Wl1, bl1, Wr1, h1, N, 0,
                                   nullptr, nullptr, nullptr, flags);
  k_layer<<<nb4, 256, 0, stream>>>(h1, rowptr, colbuf, Wl2, bl2, Wr2, h0, N, 0,
                                   nullptr, nullptr, nullptr, flags);
  k_layer<<<nb4, 256, 0, stream>>>(h0, rowptr, colbuf, Wl3, bl3, Wr3, h1, N, 1,
                                   Wo, bo, d_out, flags);
}

// Round 6
// 743.356 us; speedup vs baseline: 1.1121x; 1.0585x over previous
//
#include <hip/hip_runtime.h>
#include <stdint.h>

// ---------------------------------------------------------------------------
// FakeNewsModel: 3-layer GraphSAGE (mean agg), N=50000, E=1.6M, width 64.
// Round 9: k_project v8 — kill the SMEM serialization. Five rounds of
// counters show VALUBusy pinned at 12-16%: per-row scalar W loads (s_load)
// mixed with ds_reads force lgkmcnt(0) drains (SMEM is out-of-order) ->
// ~122-160 cyc exposed per W row, 2688 rows per SIMD = the whole kernel.
// v8 stages W tiles into LDS as PACKED bf16 (verbatim dword copy, 4KB/tile)
// double-buffered alongside x; compute reads W via wave-uniform ds_read_b128
// (broadcast, conflict-free) and unpacks at use. Pure-DS lgkm stream ->
// compiler pipelines with fine-grained lgkmcnt. xt restride 65->68 so x
// reads/writes are aligned b128 full-BW. LDS 51.2KB -> 3 blocks/CU = grid
// demand. k_layer untouched (no counters yet; next target).
//   k_detect  -> flags[0]=floats-are-bf16?, flags[1]=ints-are-int64?
//   CSR build -> memset(cnt), k_deg, k_scan1/2/3, k_scatter
//   k_project -> x0 = concat(xc@Wp+bp, xs@Ws+bs)  (fp32 h-table)
//   k_layer x3 -> relu(mean-agg@Wl + bl + x@Wr); layer 3 fuses [64,2] head.
// ---------------------------------------------------------------------------

typedef __attribute__((ext_vector_type(8))) unsigned short u16x8;
typedef __attribute__((ext_vector_type(4))) float f32x4;
typedef __attribute__((ext_vector_type(4))) unsigned int u32x4;

static __device__ __forceinline__ float bf2f(unsigned short u) {
  union { unsigned int i; float f; } v;
  v.i = ((unsigned int)u) << 16;
  return v.f;
}

static __device__ __forceinline__ unsigned short f2bf(float f) {
  union { float f; unsigned int i; } v;
  v.f = f;
  unsigned int u = v.i;
  unsigned int r = (u + 0x7FFFu + ((u >> 16) & 1u)) >> 16;  // RNE
  return (unsigned short)r;
}

template <bool BF>
static __device__ __forceinline__ float ldf(const void* p, long long i) {
  if (BF) return bf2f(((const unsigned short*)p)[i]);
  return ((const float*)p)[i];
}

static __device__ __forceinline__ int clampN(int v, int N) {
  return v < 0 ? 0 : (v >= N ? N - 1 : v);
}

// ---------------- dtype detection ----------------
__global__ void k_detect(const void* Wp, const int* ei, int* flags) {
  if (threadIdx.x == 0 && blockIdx.x == 0) {
    const unsigned short* w = (const unsigned short*)Wp;
    int bf = 1;
    for (int i = 0; i < 64; ++i) {
      float v = fabsf(bf2f(w[i]));
      if (!(v < 1.0f)) bf = 0;  // catches NaN too
    }
    flags[0] = bf;
    int i64 = 1;
    for (int i = 0; i < 32; ++i)
      if (ei[2 * i + 1] != 0) i64 = 0;
    flags[1] = i64;
  }
}

static __device__ __forceinline__ int edge_src(const int* ei, int e, int E,
                                               int i64) {
  return i64 ? ei[2 * (long long)e] : ei[e];
}
static __device__ __forceinline__ int edge_dst(const int* ei, int e, int E,
                                               int i64) {
  return i64 ? ei[2 * ((long long)E + e)] : ei[(long long)E + e];
}

// ---------------- CSR build ----------------

__global__ __launch_bounds__(256) void k_deg(const int* __restrict__ ei, int E,
                                             int N, int* __restrict__ cnt,
                                             const int* __restrict__ flags) {
  int e = blockIdx.x * 256 + threadIdx.x;
  if (e < E) {
    int d = clampN(edge_dst(ei, e, E, flags[1]), N);
    atomicAdd(&cnt[d], 1);
  }
}

__global__ __launch_bounds__(256) void k_scan1(const int* __restrict__ cnt,
                                               int* __restrict__ rowptr,
                                               int* __restrict__ bsum, int N) {
  __shared__ int sh[256];
  int t = threadIdx.x;
  int base = blockIdx.x * 1024 + t * 4;
  int v0 = 0, v1 = 0, v2 = 0, v3 = 0;
  if (base + 0 < N) v0 = cnt[base + 0];
  if (base + 1 < N) v1 = cnt[base + 1];
  if (base + 2 < N) v2 = cnt[base + 2];
  if (base + 3 < N) v3 = cnt[base + 3];
  int s = v0 + v1 + v2 + v3;
  sh[t] = s;
  __syncthreads();
  int acc = s;
  for (int off = 1; off < 256; off <<= 1) {
    int x = 0;
    if (t >= off) x = sh[t - off];
    __syncthreads();
    acc += x;
    sh[t] = acc;
    __syncthreads();
  }
  int run = acc - s;
  if (base + 0 < N) rowptr[base + 0] = run;
  run += v0;
  if (base + 1 < N) rowptr[base + 1] = run;
  run += v1;
  if (base + 2 < N) rowptr[base + 2] = run;
  run += v2;
  if (base + 3 < N) rowptr[base + 3] = run;
  run += v3;
  if (t == 255) bsum[blockIdx.x] = acc;
}

__global__ void k_scan2(int* __restrict__ bsum, int nb,
                        int* __restrict__ rowptr, int N) {
  if (threadIdx.x == 0 && blockIdx.x == 0) {
    int run = 0;
    for (int i = 0; i < nb; ++i) {
      int v = bsum[i];
      bsum[i] = run;
      run += v;
    }
    rowptr[N] = run;
  }
}

__global__ __launch_bounds__(256) void k_scan3(int* __restrict__ rowptr,
                                               int* __restrict__ cursor,
                                               const int* __restrict__ bsum,
                                               int N) {
  int i = blockIdx.x * 256 + threadIdx.x;
  if (i < N) {
    int v = rowptr[i] + bsum[i >> 10];
    rowptr[i] = v;
    cursor[i] = v;
  }
}

__global__ __launch_bounds__(256) void k_scatter(const int* __restrict__ ei,
                                                 int E, int N,
                                                 int* __restrict__ cursor,
                                                 int* __restrict__ colbuf,
                                                 const int* __restrict__ flags) {
  int e = blockIdx.x * 256 + threadIdx.x;
  if (e < E) {
    int i64 = flags[1];
    int s = clampN(edge_src(ei, e, E, i64), N);
    int d = clampN(edge_dst(ei, e, E, i64), N);
    int p = atomicAdd(&cursor[d], 1);
    if (p >= 0 && p < E) colbuf[p] = s;
  }
}

// ---------------- projection (v8: W-in-LDS, pure-DS inner loop) -------------
// Block = 256 threads = 4 waves = 64 nodes. 14 K-tiles of 64 (12 content +
// 2 style). Per tile BOTH x (64x64 f32, stride 68 -> aligned b128) and W
// (64 rows x 32 cols, packed bf16 dwords / f32) are double-buffered in LDS.
// Staging: thread (sn=tid>>2, sj=tid&3): x 16 elems + W dword-quad, loads
// issued at phase top, LDS writes after compute (T14). Compute: wave w owns
// cols [8w,8w+8); per row one wave-uniform ds_read_b128 of packed W (bf16)
// + unpack at use. All-DS lgkm stream -> fine-grained lgkmcnt pipelining.
template <bool BF>
static __device__ void project_body(const void* __restrict__ xc,
                                    const void* __restrict__ xs,
                                    const void* __restrict__ Wp,
                                    const void* __restrict__ bp,
                                    const void* __restrict__ Ws,
                                    const void* __restrict__ bs,
                                    float* __restrict__ h0, int N,
                                    float* __restrict__ lds) {
  float* xt = lds;                                          // [2][64][68] f32
  unsigned int* wtb = (unsigned int*)(lds + 2 * 64 * 68);   // BF: [2][64][16]
  float* wtf = lds + 2 * 64 * 68;                           // f32: [2][64][32]

  int tid = (int)threadIdx.x;
  int w = __builtin_amdgcn_readfirstlane(tid >> 6);  // 0..3 col-octant
  int lane = tid & 63;
  int node = (int)blockIdx.x * 64 + lane;

  int sn = tid >> 2;  // staging row 0..63
  int sj = tid & 3;   // staging quad 0..3
  int gsn = (int)blockIdx.x * 64 + sn;
  int gsnc = gsn < N ? gsn : (N - 1);

  float c[8], s[8];
#pragma unroll
  for (int r = 0; r < 8; ++r) {
    c[r] = 0.f;
    s[r] = 0.f;
  }

  // staging registers (loads land here early; LDS writes happen late)
  u16x8 pr0 = {}, pr1 = {};
  f32x4 pf0 = {}, pf1 = {}, pf2 = {}, pf3 = {};
  u32x4 wrg = {};
  f32x4 wf0 = {}, wf1 = {};

  auto stage_load = [&](int t) {
    // x chunk: 16 elems of node sn's tile-t slice
    long long idx;
    const void* src;
    if (t < 12) {
      src = xc;
      idx = (long long)gsnc * 768 + t * 64 + 16 * sj;
    } else {
      src = xs;
      idx = (long long)gsnc * 128 + (t - 12) * 64 + 16 * sj;
    }
    if (BF) {
      const unsigned short* p = (const unsigned short*)src + idx;
      pr0 = *(const u16x8*)p;
      pr1 = *(const u16x8*)(p + 8);
    } else {
      const float* p = (const float*)src + idx;
      pf0 = *(const f32x4*)(p + 0);
      pf1 = *(const f32x4*)(p + 4);
      pf2 = *(const f32x4*)(p + 8);
      pf3 = *(const f32x4*)(p + 12);
    }
    // W chunk: row sn of tile t, dword-quad sj (verbatim copy)
    int rowg = (t < 12) ? (t * 64 + sn) : ((t - 12) * 64 + sn);
    const void* wsrc = (t < 12) ? Wp : Ws;
    if (BF) {
      wrg = *(const u32x4*)((const unsigned int*)wsrc +
                            (long long)rowg * 16 + 4 * sj);
    } else {
      const float* p = (const float*)wsrc + (long long)rowg * 32 + 8 * sj;
      wf0 = *(const f32x4*)p;
      wf1 = *(const f32x4*)(p + 4);
    }
  };

  auto stage_write = [&](int t) {
    float* row = xt + (t & 1) * (64 * 68) + sn * 68 + 16 * sj;
    if (BF) {
      f32x4 v;
#pragma unroll
      for (int i = 0; i < 4; ++i) v[i] = bf2f(pr0[i]);
      *(f32x4*)(row + 0) = v;
#pragma unroll
      for (int i = 0; i < 4; ++i) v[i] = bf2f(pr0[4 + i]);
      *(f32x4*)(row + 4) = v;
#pragma unroll
      for (int i = 0; i < 4; ++i) v[i] = bf2f(pr1[i]);
      *(f32x4*)(row + 8) = v;
#pragma unroll
      for (int i = 0; i < 4; ++i) v[i] = bf2f(pr1[4 + i]);
      *(f32x4*)(row + 12) = v;
    } else {
      *(f32x4*)(row + 0) = pf0;
      *(f32x4*)(row + 4) = pf1;
      *(f32x4*)(row + 8) = pf2;
      *(f32x4*)(row + 12) = pf3;
    }
    if (BF) {
      *(u32x4*)(wtb + (t & 1) * (64 * 16) + sn * 16 + 4 * sj) = wrg;
    } else {
      float* wrow = wtf + (t & 1) * (64 * 32) + sn * 32 + 8 * sj;
      *(f32x4*)wrow = wf0;
      *(f32x4*)(wrow + 4) = wf1;
    }
  };

  // prologue: stage tile 0
  stage_load(0);
  stage_write(0);
  __syncthreads();

#pragma unroll 1
  for (int t = 0; t < 14; ++t) {
    if (t + 1 < 14) stage_load(t + 1);  // issue global loads early (T14)

    const float* xrow = xt + (t & 1) * (64 * 68) + lane * 68;
    if (BF) {
      const unsigned int* wbase = wtb + (t & 1) * (64 * 16) + 4 * w;
      if (t < 12) {
#pragma unroll 2
        for (int k0 = 0; k0 < 64; k0 += 4) {
          f32x4 x4 = *(const f32x4*)(xrow + k0);
#pragma unroll
          for (int kk = 0; kk < 4; ++kk) {
            u32x4 wp4 = *(const u32x4*)(wbase + (k0 + kk) * 16);  // uniform
#pragma unroll
            for (int p = 0; p < 4; ++p) {
              union { unsigned int i; float f; } lo, hi;
              lo.i = wp4[p] << 16;
              hi.i = wp4[p] & 0xFFFF0000u;
              c[2 * p + 0] += x4[kk] * lo.f;
              c[2 * p + 1] += x4[kk] * hi.f;
            }
          }
        }
      } else {
#pragma unroll 2
        for (int k0 = 0; k0 < 64; k0 += 4) {
          f32x4 x4 = *(const f32x4*)(xrow + k0);
#pragma unroll
          for (int kk = 0; kk < 4; ++kk) {
            u32x4 wp4 = *(const u32x4*)(wbase + (k0 + kk) * 16);  // uniform
#pragma unroll
            for (int p = 0; p < 4; ++p) {
              union { unsigned int i; float f; } lo, hi;
              lo.i = wp4[p] << 16;
              hi.i = wp4[p] & 0xFFFF0000u;
              s[2 * p + 0] += x4[kk] * lo.f;
              s[2 * p + 1] += x4[kk] * hi.f;
            }
          }
        }
      }
    } else {
      const float* wbase = wtf + (t & 1) * (64 * 32) + 8 * w;
      if (t < 12) {
#pragma unroll 2
        for (int k0 = 0; k0 < 64; k0 += 4) {
          f32x4 x4 = *(const f32x4*)(xrow + k0);
#pragma unroll
          for (int kk = 0; kk < 4; ++kk) {
            const float* wr = wbase + (k0 + kk) * 32;
            f32x4 wa = *(const f32x4*)wr;           // uniform
            f32x4 wb = *(const f32x4*)(wr + 4);     // uniform
#pragma unroll
            for (int r = 0; r < 4; ++r) {
              c[r] += x4[kk] * wa[r];
              c[4 + r] += x4[kk] * wb[r];
            }
          }
        }
      } else {
#pragma unroll 2
        for (int k0 = 0; k0 < 64; k0 += 4) {
          f32x4 x4 = *(const f32x4*)(xrow + k0);
#pragma unroll
          for (int kk = 0; kk < 4; ++kk) {
            const float* wr = wbase + (k0 + kk) * 32;
            f32x4 wa = *(const f32x4*)wr;
            f32x4 wb = *(const f32x4*)(wr + 4);
#pragma unroll
            for (int r = 0; r < 4; ++r) {
              s[r] += x4[kk] * wa[r];
              s[4 + r] += x4[kk] * wb[r];
            }
          }
        }
      }
    }

    if (t + 1 < 14) stage_write(t + 1);  // LDS writes late (vmcnt lands here)
    __syncthreads();
  }

  if (node < N) {
    float* orow = h0 + (long long)node * 64;
    f32x4 v;
#pragma unroll
    for (int r = 0; r < 4; ++r) v[r] = c[r] + ldf<BF>(bp, 8 * w + r);
    *(f32x4*)(orow + 8 * w) = v;
#pragma unroll
    for (int r = 0; r < 4; ++r) v[r] = c[4 + r] + ldf<BF>(bp, 8 * w + 4 + r);
    *(f32x4*)(orow + 8 * w + 4) = v;
#pragma unroll
    for (int r = 0; r < 4; ++r) v[r] = s[r] + ldf<BF>(bs, 8 * w + r);
    *(f32x4*)(orow + 32 + 8 * w) = v;
#pragma unroll
    for (int r = 0; r < 4; ++r) v[r] = s[4 + r] + ldf<BF>(bs, 8 * w + 4 + r);
    *(f32x4*)(orow + 32 + 8 * w + 4) = v;
  }
}

__global__ __launch_bounds__(256) void k_project(
    const void* __restrict__ xc, const void* __restrict__ xs,
    const void* __restrict__ Wp, const void* __restrict__ bp,
    const void* __restrict__ Ws, const void* __restrict__ bs,
    float* __restrict__ h0, int N, const int* __restrict__ flags) {
  // xt [2][64][68] f32 (34816 B) + wt (f32 layout, 16384 B) = 51200 B
  __shared__ float lds[2 * 64 * 68 + 2 * 64 * 32];
  if (flags[0])
    project_body<true>(xc, xs, Wp, bp, Ws, bs, h0, N, lds);
  else
    project_body<false>(xc, xs, Wp, bp, Ws, bs, h0, N, lds);
}

// ---------------- SAGE layer ----------------
template <bool BF>
static __device__ void layer_body(const float* __restrict__ hin,
                                  const int* __restrict__ rowptr,
                                  const int* __restrict__ colbuf,
                                  const void* Wl, const void* bl,
                                  const void* Wr, float* __restrict__ hout,
                                  int N, int last, const void* Wo,
                                  const void* bo, void* outp) {
  int node = (int)((blockIdx.x * blockDim.x + threadIdx.x) >> 6);
  int lane = (int)(threadIdx.x & 63);
  if (node >= N) return;
  int rs = rowptr[node], re = rowptr[node + 1];
  float xself = hin[(long long)node * 64 + lane];
  float agg0 = 0.f, agg1 = 0.f, agg2 = 0.f, agg3 = 0.f;
  float agg4 = 0.f, agg5 = 0.f, agg6 = 0.f, agg7 = 0.f;
  for (int cb = rs; cb < re; cb += 64) {
    int sidx = 0;
    if (cb + lane < re) sidx = clampN(colbuf[cb + lane], N);
    int c = re - cb;
    if (c > 64) c = 64;
    int t = 0;
    for (; t + 8 <= c; t += 8) {
      int s0 = __builtin_amdgcn_readlane(sidx, t + 0);
      int s1 = __builtin_amdgcn_readlane(sidx, t + 1);
      int s2 = __builtin_amdgcn_readlane(sidx, t + 2);
      int s3 = __builtin_amdgcn_readlane(sidx, t + 3);
      int s4 = __builtin_amdgcn_readlane(sidx, t + 4);
      int s5 = __builtin_amdgcn_readlane(sidx, t + 5);
      int s6 = __builtin_amdgcn_readlane(sidx, t + 6);
      int s7 = __builtin_amdgcn_readlane(sidx, t + 7);
      float v0 = hin[(long long)s0 * 64 + lane];
      float v1 = hin[(long long)s1 * 64 + lane];
      float v2 = hin[(long long)s2 * 64 + lane];
      float v3 = hin[(long long)s3 * 64 + lane];
      float v4 = hin[(long long)s4 * 64 + lane];
      float v5 = hin[(long long)s5 * 64 + lane];
      float v6 = hin[(long long)s6 * 64 + lane];
      float v7 = hin[(long long)s7 * 64 + lane];
      agg0 += v0;
      agg1 += v1;
      agg2 += v2;
      agg3 += v3;
      agg4 += v4;
      agg5 += v5;
      agg6 += v6;
      agg7 += v7;
    }
    for (; t < c; ++t) {
      int s = __builtin_amdgcn_readlane(sidx, t);
      agg0 += hin[(long long)s * 64 + lane];
    }
  }
  float agg = ((agg0 + agg1) + (agg2 + agg3)) + ((agg4 + agg5) + (agg6 + agg7));
  int deg = re - rs;
  if (deg > 0) agg *= (1.f / (float)deg);

  float o = ldf<BF>(bl, lane);
#pragma unroll 8
  for (int d = 0; d < 64; ++d) {
    float ad = __uint_as_float(
        __builtin_amdgcn_readlane(__float_as_uint(agg), d));
    float xd = __uint_as_float(
        __builtin_amdgcn_readlane(__float_as_uint(xself), d));
    o += ad * ldf<BF>(Wl, d * 64 + lane);
    o += xd * ldf<BF>(Wr, d * 64 + lane);
  }
  o = fmaxf(o, 0.f);

  if (!last) {
    hout[(long long)node * 64 + lane] = o;
  } else {
    float c0 = o * ldf<BF>(Wo, lane * 2 + 0);
    float c1 = o * ldf<BF>(Wo, lane * 2 + 1);
    for (int off = 32; off > 0; off >>= 1) {
      c0 += __shfl_xor(c0, off, 64);
      c1 += __shfl_xor(c1, off, 64);
    }
    if (lane == 0) {
      float r0 = c0 + ldf<BF>(bo, 0);
      float r1 = c1 + ldf<BF>(bo, 1);
      if (BF) {
        unsigned short* o16 = (unsigned short*)outp;
        o16[(long long)node * 2 + 0] = f2bf(r0);
        o16[(long long)node * 2 + 1] = f2bf(r1);
      } else {
        float* o32 = (float*)outp;
        o32[(long long)node * 2 + 0] = r0;
        o32[(long long)node * 2 + 1] = r1;
      }
    }
  }
}

__global__ __launch_bounds__(256) void k_layer(
    const float* hin, const int* rowptr, const int* colbuf, const void* Wl,
    const void* bl, const void* Wr, float* hout, int N, int last,
    const void* Wo, const void* bo, void* outp, const int* __restrict__ flags) {
  if (flags[0])
    layer_body<true>(hin, rowptr, colbuf, Wl, bl, Wr, hout, N, last, Wo, bo,
                     outp);
  else
    layer_body<false>(hin, rowptr, colbuf, Wl, bl, Wr, hout, N, last, Wo, bo,
                      outp);
}

// ---------------- host ----------------

extern "C" void kernel_launch(void* const* d_in, const int* in_sizes, int n_in,
                              void* d_out, int out_size, void* d_ws,
                              size_t ws_size, hipStream_t stream) {
  const void* xc = d_in[0];
  const void* xs = d_in[1];
  const int* ei = (const int*)d_in[2];
  const void* Wp = d_in[4];
  const void* bp = d_in[5];
  const void* Ws = d_in[6];
  const void* bs = d_in[7];
  const void* Wl1 = d_in[8];
  const void* bl1 = d_in[9];
  const void* Wr1 = d_in[10];
  const void* Wl2 = d_in[11];
  const void* bl2 = d_in[12];
  const void* Wr2 = d_in[13];
  const void* Wl3 = d_in[14];
  const void* bl3 = d_in[15];
  const void* Wr3 = d_in[16];
  const void* Wo = d_in[17];
  const void* bo = d_in[18];

  int N = out_size / 2;   // output is [N, 2]
  int E = in_sizes[3];    // edge_type has E elements

  char* ws = (char*)d_ws;
  size_t off = 0;
  auto alloc = [&](size_t bytes) {
    char* p = ws + off;
    off += (bytes + 255) & ~(size_t)255;
    return p;
  };
  int* colbuf = (int*)alloc((size_t)E * 4);
  int* cnt = (int*)alloc((size_t)N * 4);
  int* rowptr = (int*)alloc((size_t)(N + 1) * 4);
  int* cursor = (int*)alloc((size_t)N * 4);
  int* bsum = (int*)alloc(4096);
  int* flags = (int*)alloc(256);
  float* h0 = (float*)alloc((size_t)N * 64 * 4);
  float* h1 = (float*)alloc((size_t)N * 64 * 4);
  (void)ws_size;
  (void)n_in;

  k_detect<<<1, 64, 0, stream>>>(Wp, ei, flags);

  hipMemsetAsync(cnt, 0, (size_t)N * 4, stream);
  int eb = (E + 255) / 256;
  k_deg<<<eb, 256, 0, stream>>>(ei, E, N, cnt, flags);
  int sb = (N + 1023) / 1024;
  k_scan1<<<sb, 256, 0, stream>>>(cnt, rowptr, bsum, N);
  k_scan2<<<1, 64, 0, stream>>>(bsum, sb, rowptr, N);
  k_scan3<<<(N + 255) / 256, 256, 0, stream>>>(rowptr, cursor, bsum, N);
  k_scatter<<<eb, 256, 0, stream>>>(ei, E, N, cursor, colbuf, flags);

  int pb = (N + 63) / 64;  // 64 nodes per 256-thread block (4 waves)
  k_project<<<pb, 256, 0, stream>>>(xc, xs, Wp, bp, Ws, bs, h0, N, flags);

  int nb4 = (N + 3) / 4;  // 4 waves (nodes) per 256-thread block
  k_layer<<<nb4, 256, 0, stream>>>(h0, rowptr, colbuf, Wl1, bl1, Wr1, h1, N, 0,
                                   nullptr, nullptr, nullptr, flags);
  k_layer<<<nb4, 256, 0, stream>>>(h1, rowptr, colbuf, Wl2, bl2, Wr2, h0, N, 0,
                                   nullptr, nullptr, nullptr, flags);
  k_layer<<<nb4, 256, 0, stream>>>(h0, rowptr, colbuf, Wl3, bl3, Wr3, h1, N, 1,
                                   Wo, bo, d_out, flags);
}

// Round 7
// 730.234 us; speedup vs baseline: 1.1321x; 1.0180x over previous
//
#include <hip/hip_runtime.h>
#include <stdint.h>

// ---------------------------------------------------------------------------
// FakeNewsModel: 3-layer GraphSAGE (mean agg), N=50000, E=1.6M, width 64.
// Round 10: kill k_scatter's 16x write amplification. Round-9 counters:
// k_scatter #1 at 118us, WRITE_SIZE=101MB for 6.4MB useful (E random 4B
// stores -> one 64B line writeback each, ~0.95 TB/s random-line ceiling,
// VALUBusy 0.75%). Fix = temporal clustering: k_pack merges deg-count with
// packing (src,dst) into a compact int2 stream (aliases h0: E*8B == N*256B);
// then 8 scatter passes, pass r writes only dst in [r*6250,(r+1)*6250) ->
// colbuf write window ~800KB = L2-resident -> lines pack fully before
// eviction. Passes stream pairs[] coalesced at sequential BW.
// k_project (round-9 W-in-LDS version) and k_layer unchanged.
//   k_detect  -> flags[0]=floats-are-bf16?, flags[1]=ints-are-int64?
//   CSR build -> memset(cnt), k_pack, k_scan1/2/3, k_scatter2 x8
//   k_project -> x0 = concat(xc@Wp+bp, xs@Ws+bs)  (fp32 h-table)
//   k_layer x3 -> relu(mean-agg@Wl + bl + x@Wr); layer 3 fuses [64,2] head.
// ---------------------------------------------------------------------------

typedef __attribute__((ext_vector_type(8))) unsigned short u16x8;
typedef __attribute__((ext_vector_type(4))) float f32x4;
typedef __attribute__((ext_vector_type(4))) unsigned int u32x4;
typedef __attribute__((ext_vector_type(2))) int i32x2;

static __device__ __forceinline__ float bf2f(unsigned short u) {
  union { unsigned int i; float f; } v;
  v.i = ((unsigned int)u) << 16;
  return v.f;
}

static __device__ __forceinline__ unsigned short f2bf(float f) {
  union { float f; unsigned int i; } v;
  v.f = f;
  unsigned int u = v.i;
  unsigned int r = (u + 0x7FFFu + ((u >> 16) & 1u)) >> 16;  // RNE
  return (unsigned short)r;
}

template <bool BF>
static __device__ __forceinline__ float ldf(const void* p, long long i) {
  if (BF) return bf2f(((const unsigned short*)p)[i]);
  return ((const float*)p)[i];
}

static __device__ __forceinline__ int clampN(int v, int N) {
  return v < 0 ? 0 : (v >= N ? N - 1 : v);
}

// ---------------- dtype detection ----------------
__global__ void k_detect(const void* Wp, const int* ei, int* flags) {
  if (threadIdx.x == 0 && blockIdx.x == 0) {
    const unsigned short* w = (const unsigned short*)Wp;
    int bf = 1;
    for (int i = 0; i < 64; ++i) {
      float v = fabsf(bf2f(w[i]));
      if (!(v < 1.0f)) bf = 0;  // catches NaN too
    }
    flags[0] = bf;
    int i64 = 1;
    for (int i = 0; i < 32; ++i)
      if (ei[2 * i + 1] != 0) i64 = 0;
    flags[1] = i64;
  }
}

static __device__ __forceinline__ int edge_src(const int* ei, int e, int E,
                                               int i64) {
  return i64 ? ei[2 * (long long)e] : ei[e];
}
static __device__ __forceinline__ int edge_dst(const int* ei, int e, int E,
                                               int i64) {
  return i64 ? ei[2 * ((long long)E + e)] : ei[(long long)E + e];
}

// ---------------- CSR build ----------------

// pack (src,dst) into a compact coalesced stream + count degrees.
__global__ __launch_bounds__(256) void k_pack(const int* __restrict__ ei, int E,
                                              int N, int* __restrict__ cnt,
                                              i32x2* __restrict__ pairs,
                                              const int* __restrict__ flags) {
  int e = blockIdx.x * 256 + threadIdx.x;
  if (e < E) {
    int i64 = flags[1];
    int s = clampN(edge_src(ei, e, E, i64), N);
    int d = clampN(edge_dst(ei, e, E, i64), N);
    i32x2 p;
    p[0] = s;
    p[1] = d;
    pairs[e] = p;
    atomicAdd(&cnt[d], 1);
  }
}

__global__ __launch_bounds__(256) void k_scan1(const int* __restrict__ cnt,
                                               int* __restrict__ rowptr,
                                               int* __restrict__ bsum, int N) {
  __shared__ int sh[256];
  int t = threadIdx.x;
  int base = blockIdx.x * 1024 + t * 4;
  int v0 = 0, v1 = 0, v2 = 0, v3 = 0;
  if (base + 0 < N) v0 = cnt[base + 0];
  if (base + 1 < N) v1 = cnt[base + 1];
  if (base + 2 < N) v2 = cnt[base + 2];
  if (base + 3 < N) v3 = cnt[base + 3];
  int s = v0 + v1 + v2 + v3;
  sh[t] = s;
  __syncthreads();
  int acc = s;
  for (int off = 1; off < 256; off <<= 1) {
    int x = 0;
    if (t >= off) x = sh[t - off];
    __syncthreads();
    acc += x;
    sh[t] = acc;
    __syncthreads();
  }
  int run = acc - s;
  if (base + 0 < N) rowptr[base + 0] = run;
  run += v0;
  if (base + 1 < N) rowptr[base + 1] = run;
  run += v1;
  if (base + 2 < N) rowptr[base + 2] = run;
  run += v2;
  if (base + 3 < N) rowptr[base + 3] = run;
  run += v3;
  if (t == 255) bsum[blockIdx.x] = acc;
}

__global__ void k_scan2(int* __restrict__ bsum, int nb,
                        int* __restrict__ rowptr, int N) {
  if (threadIdx.x == 0 && blockIdx.x == 0) {
    int run = 0;
    for (int i = 0; i < nb; ++i) {
      int v = bsum[i];
      bsum[i] = run;
      run += v;
    }
    rowptr[N] = run;
  }
}

__global__ __launch_bounds__(256) void k_scan3(int* __restrict__ rowptr,
                                               int* __restrict__ cursor,
                                               const int* __restrict__ bsum,
                                               int N) {
  int i = blockIdx.x * 256 + threadIdx.x;
  if (i < N) {
    int v = rowptr[i] + bsum[i >> 10];
    rowptr[i] = v;
    cursor[i] = v;
  }
}

// one dst-range pass: only edges with dst in [lo,hi) write. The pass's
// colbuf window (~E/8*4B ~ 800KB) stays L2-resident -> full line packing.
__global__ __launch_bounds__(256) void k_scatter2(
    const i32x2* __restrict__ pairs, int E, int lo, int hi,
    int* __restrict__ cursor, int* __restrict__ colbuf) {
  int e = blockIdx.x * 256 + threadIdx.x;
  if (e < E) {
    i32x2 p2 = pairs[e];
    int d = p2[1];
    if (d >= lo && d < hi) {
      int p = atomicAdd(&cursor[d], 1);
      if (p >= 0 && p < E) colbuf[p] = p2[0];
    }
  }
}

// ---------------- projection (v8: W-in-LDS, pure-DS inner loop) -------------
// Block = 256 threads = 4 waves = 64 nodes. 14 K-tiles of 64 (12 content +
// 2 style). Per tile BOTH x (64x64 f32, stride 68 -> aligned b128) and W
// (64 rows x 32 cols, packed bf16 dwords / f32) are double-buffered in LDS.
// Staging: thread (sn=tid>>2, sj=tid&3): x 16 elems + W dword-quad, loads
// issued at phase top, LDS writes after compute (T14). Compute: wave w owns
// cols [8w,8w+8); per row one wave-uniform ds_read_b128 of packed W (bf16)
// + unpack at use. All-DS lgkm stream -> fine-grained lgkmcnt pipelining.
template <bool BF>
static __device__ void project_body(const void* __restrict__ xc,
                                    const void* __restrict__ xs,
                                    const void* __restrict__ Wp,
                                    const void* __restrict__ bp,
                                    const void* __restrict__ Ws,
                                    const void* __restrict__ bs,
                                    float* __restrict__ h0, int N,
                                    float* __restrict__ lds) {
  float* xt = lds;                                          // [2][64][68] f32
  unsigned int* wtb = (unsigned int*)(lds + 2 * 64 * 68);   // BF: [2][64][16]
  float* wtf = lds + 2 * 64 * 68;                           // f32: [2][64][32]

  int tid = (int)threadIdx.x;
  int w = __builtin_amdgcn_readfirstlane(tid >> 6);  // 0..3 col-octant
  int lane = tid & 63;
  int node = (int)blockIdx.x * 64 + lane;

  int sn = tid >> 2;  // staging row 0..63
  int sj = tid & 3;   // staging quad 0..3
  int gsn = (int)blockIdx.x * 64 + sn;
  int gsnc = gsn < N ? gsn : (N - 1);

  float c[8], s[8];
#pragma unroll
  for (int r = 0; r < 8; ++r) {
    c[r] = 0.f;
    s[r] = 0.f;
  }

  // staging registers (loads land here early; LDS writes happen late)
  u16x8 pr0 = {}, pr1 = {};
  f32x4 pf0 = {}, pf1 = {}, pf2 = {}, pf3 = {};
  u32x4 wrg = {};
  f32x4 wf0 = {}, wf1 = {};

  auto stage_load = [&](int t) {
    // x chunk: 16 elems of node sn's tile-t slice
    long long idx;
    const void* src;
    if (t < 12) {
      src = xc;
      idx = (long long)gsnc * 768 + t * 64 + 16 * sj;
    } else {
      src = xs;
      idx = (long long)gsnc * 128 + (t - 12) * 64 + 16 * sj;
    }
    if (BF) {
      const unsigned short* p = (const unsigned short*)src + idx;
      pr0 = *(const u16x8*)p;
      pr1 = *(const u16x8*)(p + 8);
    } else {
      const float* p = (const float*)src + idx;
      pf0 = *(const f32x4*)(p + 0);
      pf1 = *(const f32x4*)(p + 4);
      pf2 = *(const f32x4*)(p + 8);
      pf3 = *(const f32x4*)(p + 12);
    }
    // W chunk: row sn of tile t, dword-quad sj (verbatim copy)
    int rowg = (t < 12) ? (t * 64 + sn) : ((t - 12) * 64 + sn);
    const void* wsrc = (t < 12) ? Wp : Ws;
    if (BF) {
      wrg = *(const u32x4*)((const unsigned int*)wsrc +
                            (long long)rowg * 16 + 4 * sj);
    } else {
      const float* p = (const float*)wsrc + (long long)rowg * 32 + 8 * sj;
      wf0 = *(const f32x4*)p;
      wf1 = *(const f32x4*)(p + 4);
    }
  };

  auto stage_write = [&](int t) {
    float* row = xt + (t & 1) * (64 * 68) + sn * 68 + 16 * sj;
    if (BF) {
      f32x4 v;
#pragma unroll
      for (int i = 0; i < 4; ++i) v[i] = bf2f(pr0[i]);
      *(f32x4*)(row + 0) = v;
#pragma unroll
      for (int i = 0; i < 4; ++i) v[i] = bf2f(pr0[4 + i]);
      *(f32x4*)(row + 4) = v;
#pragma unroll
      for (int i = 0; i < 4; ++i) v[i] = bf2f(pr1[i]);
      *(f32x4*)(row + 8) = v;
#pragma unroll
      for (int i = 0; i < 4; ++i) v[i] = bf2f(pr1[4 + i]);
      *(f32x4*)(row + 12) = v;
    } else {
      *(f32x4*)(row + 0) = pf0;
      *(f32x4*)(row + 4) = pf1;
      *(f32x4*)(row + 8) = pf2;
      *(f32x4*)(row + 12) = pf3;
    }
    if (BF) {
      *(u32x4*)(wtb + (t & 1) * (64 * 16) + sn * 16 + 4 * sj) = wrg;
    } else {
      float* wrow = wtf + (t & 1) * (64 * 32) + sn * 32 + 8 * sj;
      *(f32x4*)wrow = wf0;
      *(f32x4*)(wrow + 4) = wf1;
    }
  };

  // prologue: stage tile 0
  stage_load(0);
  stage_write(0);
  __syncthreads();

#pragma unroll 1
  for (int t = 0; t < 14; ++t) {
    if (t + 1 < 14) stage_load(t + 1);  // issue global loads early (T14)

    const float* xrow = xt + (t & 1) * (64 * 68) + lane * 68;
    if (BF) {
      const unsigned int* wbase = wtb + (t & 1) * (64 * 16) + 4 * w;
      if (t < 12) {
#pragma unroll 2
        for (int k0 = 0; k0 < 64; k0 += 4) {
          f32x4 x4 = *(const f32x4*)(xrow + k0);
#pragma unroll
          for (int kk = 0; kk < 4; ++kk) {
            u32x4 wp4 = *(const u32x4*)(wbase + (k0 + kk) * 16);  // uniform
#pragma unroll
            for (int p = 0; p < 4; ++p) {
              union { unsigned int i; float f; } lo, hi;
              lo.i = wp4[p] << 16;
              hi.i = wp4[p] & 0xFFFF0000u;
              c[2 * p + 0] += x4[kk] * lo.f;
              c[2 * p + 1] += x4[kk] * hi.f;
            }
          }
        }
      } else {
#pragma unroll 2
        for (int k0 = 0; k0 < 64; k0 += 4) {
          f32x4 x4 = *(const f32x4*)(xrow + k0);
#pragma unroll
          for (int kk = 0; kk < 4; ++kk) {
            u32x4 wp4 = *(const u32x4*)(wbase + (k0 + kk) * 16);  // uniform
#pragma unroll
            for (int p = 0; p < 4; ++p) {
              union { unsigned int i; float f; } lo, hi;
              lo.i = wp4[p] << 16;
              hi.i = wp4[p] & 0xFFFF0000u;
              s[2 * p + 0] += x4[kk] * lo.f;
              s[2 * p + 1] += x4[kk] * hi.f;
            }
          }
        }
      }
    } else {
      const float* wbase = wtf + (t & 1) * (64 * 32) + 8 * w;
      if (t < 12) {
#pragma unroll 2
        for (int k0 = 0; k0 < 64; k0 += 4) {
          f32x4 x4 = *(const f32x4*)(xrow + k0);
#pragma unroll
          for (int kk = 0; kk < 4; ++kk) {
            const float* wr = wbase + (k0 + kk) * 32;
            f32x4 wa = *(const f32x4*)wr;           // uniform
            f32x4 wb = *(const f32x4*)(wr + 4);     // uniform
#pragma unroll
            for (int r = 0; r < 4; ++r) {
              c[r] += x4[kk] * wa[r];
              c[4 + r] += x4[kk] * wb[r];
            }
          }
        }
      } else {
#pragma unroll 2
        for (int k0 = 0; k0 < 64; k0 += 4) {
          f32x4 x4 = *(const f32x4*)(xrow + k0);
#pragma unroll
          for (int kk = 0; kk < 4; ++kk) {
            const float* wr = wbase + (k0 + kk) * 32;
            f32x4 wa = *(const f32x4*)wr;
            f32x4 wb = *(const f32x4*)(wr + 4);
#pragma unroll
            for (int r = 0; r < 4; ++r) {
              s[r] += x4[kk] * wa[r];
              s[4 + r] += x4[kk] * wb[r];
            }
          }
        }
      }
    }

    if (t + 1 < 14) stage_write(t + 1);  // LDS writes late (vmcnt lands here)
    __syncthreads();
  }

  if (node < N) {
    float* orow = h0 + (long long)node * 64;
    f32x4 v;
#pragma unroll
    for (int r = 0; r < 4; ++r) v[r] = c[r] + ldf<BF>(bp, 8 * w + r);
    *(f32x4*)(orow + 8 * w) = v;
#pragma unroll
    for (int r = 0; r < 4; ++r) v[r] = c[4 + r] + ldf<BF>(bp, 8 * w + 4 + r);
    *(f32x4*)(orow + 8 * w + 4) = v;
#pragma unroll
    for (int r = 0; r < 4; ++r) v[r] = s[r] + ldf<BF>(bs, 8 * w + r);
    *(f32x4*)(orow + 32 + 8 * w) = v;
#pragma unroll
    for (int r = 0; r < 4; ++r) v[r] = s[4 + r] + ldf<BF>(bs, 8 * w + 4 + r);
    *(f32x4*)(orow + 32 + 8 * w + 4) = v;
  }
}

__global__ __launch_bounds__(256) void k_project(
    const void* __restrict__ xc, const void* __restrict__ xs,
    const void* __restrict__ Wp, const void* __restrict__ bp,
    const void* __restrict__ Ws, const void* __restrict__ bs,
    float* __restrict__ h0, int N, const int* __restrict__ flags) {
  // xt [2][64][68] f32 (34816 B) + wt (f32 layout, 16384 B) = 51200 B
  __shared__ float lds[2 * 64 * 68 + 2 * 64 * 32];
  if (flags[0])
    project_body<true>(xc, xs, Wp, bp, Ws, bs, h0, N, lds);
  else
    project_body<false>(xc, xs, Wp, bp, Ws, bs, h0, N, lds);
}

// ---------------- SAGE layer ----------------
template <bool BF>
static __device__ void layer_body(const float* __restrict__ hin,
                                  const int* __restrict__ rowptr,
                                  const int* __restrict__ colbuf,
                                  const void* Wl, const void* bl,
                                  const void* Wr, float* __restrict__ hout,
                                  int N, int last, const void* Wo,
                                  const void* bo, void* outp) {
  int node = (int)((blockIdx.x * blockDim.x + threadIdx.x) >> 6);
  int lane = (int)(threadIdx.x & 63);
  if (node >= N) return;
  int rs = rowptr[node], re = rowptr[node + 1];
  float xself = hin[(long long)node * 64 + lane];
  float agg0 = 0.f, agg1 = 0.f, agg2 = 0.f, agg3 = 0.f;
  float agg4 = 0.f, agg5 = 0.f, agg6 = 0.f, agg7 = 0.f;
  for (int cb = rs; cb < re; cb += 64) {
    int sidx = 0;
    if (cb + lane < re) sidx = clampN(colbuf[cb + lane], N);
    int c = re - cb;
    if (c > 64) c = 64;
    int t = 0;
    for (; t + 8 <= c; t += 8) {
      int s0 = __builtin_amdgcn_readlane(sidx, t + 0);
      int s1 = __builtin_amdgcn_readlane(sidx, t + 1);
      int s2 = __builtin_amdgcn_readlane(sidx, t + 2);
      int s3 = __builtin_amdgcn_readlane(sidx, t + 3);
      int s4 = __builtin_amdgcn_readlane(sidx, t + 4);
      int s5 = __builtin_amdgcn_readlane(sidx, t + 5);
      int s6 = __builtin_amdgcn_readlane(sidx, t + 6);
      int s7 = __builtin_amdgcn_readlane(sidx, t + 7);
      float v0 = hin[(long long)s0 * 64 + lane];
      float v1 = hin[(long long)s1 * 64 + lane];
      float v2 = hin[(long long)s2 * 64 + lane];
      float v3 = hin[(long long)s3 * 64 + lane];
      float v4 = hin[(long long)s4 * 64 + lane];
      float v5 = hin[(long long)s5 * 64 + lane];
      float v6 = hin[(long long)s6 * 64 + lane];
      float v7 = hin[(long long)s7 * 64 + lane];
      agg0 += v0;
      agg1 += v1;
      agg2 += v2;
      agg3 += v3;
      agg4 += v4;
      agg5 += v5;
      agg6 += v6;
      agg7 += v7;
    }
    for (; t < c; ++t) {
      int s = __builtin_amdgcn_readlane(sidx, t);
      agg0 += hin[(long long)s * 64 + lane];
    }
  }
  float agg = ((agg0 + agg1) + (agg2 + agg3)) + ((agg4 + agg5) + (agg6 + agg7));
  int deg = re - rs;
  if (deg > 0) agg *= (1.f / (float)deg);

  float o = ldf<BF>(bl, lane);
#pragma unroll 8
  for (int d = 0; d < 64; ++d) {
    float ad = __uint_as_float(
        __builtin_amdgcn_readlane(__float_as_uint(agg), d));
    float xd = __uint_as_float(
        __builtin_amdgcn_readlane(__float_as_uint(xself), d));
    o += ad * ldf<BF>(Wl, d * 64 + lane);
    o += xd * ldf<BF>(Wr, d * 64 + lane);
  }
  o = fmaxf(o, 0.f);

  if (!last) {
    hout[(long long)node * 64 + lane] = o;
  } else {
    float c0 = o * ldf<BF>(Wo, lane * 2 + 0);
    float c1 = o * ldf<BF>(Wo, lane * 2 + 1);
    for (int off = 32; off > 0; off >>= 1) {
      c0 += __shfl_xor(c0, off, 64);
      c1 += __shfl_xor(c1, off, 64);
    }
    if (lane == 0) {
      float r0 = c0 + ldf<BF>(bo, 0);
      float r1 = c1 + ldf<BF>(bo, 1);
      if (BF) {
        unsigned short* o16 = (unsigned short*)outp;
        o16[(long long)node * 2 + 0] = f2bf(r0);
        o16[(long long)node * 2 + 1] = f2bf(r1);
      } else {
        float* o32 = (float*)outp;
        o32[(long long)node * 2 + 0] = r0;
        o32[(long long)node * 2 + 1] = r1;
      }
    }
  }
}

__global__ __launch_bounds__(256) void k_layer(
    const float* hin, const int* rowptr, const int* colbuf, const void* Wl,
    const void* bl, const void* Wr, float* hout, int N, int last,
    const void* Wo, const void* bo, void* outp, const int* __restrict__ flags) {
  if (flags[0])
    layer_body<true>(hin, rowptr, colbuf, Wl, bl, Wr, hout, N, last, Wo, bo,
                     outp);
  else
    layer_body<false>(hin, rowptr, colbuf, Wl, bl, Wr, hout, N, last, Wo, bo,
                      outp);
}

// ---------------- host ----------------

extern "C" void kernel_launch(void* const* d_in, const int* in_sizes, int n_in,
                              void* d_out, int out_size, void* d_ws,
                              size_t ws_size, hipStream_t stream) {
  const void* xc = d_in[0];
  const void* xs = d_in[1];
  const int* ei = (const int*)d_in[2];
  const void* Wp = d_in[4];
  const void* bp = d_in[5];
  const void* Ws = d_in[6];
  const void* bs = d_in[7];
  const void* Wl1 = d_in[8];
  const void* bl1 = d_in[9];
  const void* Wr1 = d_in[10];
  const void* Wl2 = d_in[11];
  const void* bl2 = d_in[12];
  const void* Wr2 = d_in[13];
  const void* Wl3 = d_in[14];
  const void* bl3 = d_in[15];
  const void* Wr3 = d_in[16];
  const void* Wo = d_in[17];
  const void* bo = d_in[18];

  int N = out_size / 2;   // output is [N, 2]
  int E = in_sizes[3];    // edge_type has E elements

  char* ws = (char*)d_ws;
  size_t off = 0;
  auto alloc = [&](size_t bytes) {
    char* p = ws + off;
    off += (bytes + 255) & ~(size_t)255;
    return p;
  };
  int* colbuf = (int*)alloc((size_t)E * 4);
  int* cnt = (int*)alloc((size_t)N * 4);
  int* rowptr = (int*)alloc((size_t)(N + 1) * 4);
  int* cursor = (int*)alloc((size_t)N * 4);
  int* bsum = (int*)alloc(4096);
  int* flags = (int*)alloc(256);
  float* h0 = (float*)alloc((size_t)N * 64 * 4);
  float* h1 = (float*)alloc((size_t)N * 64 * 4);
  (void)ws_size;
  (void)n_in;

  // pairs (E * 8B) aliases h0 (N*64*4B = 12.8MB >= E*8B = 12.8MB):
  // written by k_pack, consumed by the scatter passes, then h0 is
  // overwritten by k_project (stream-ordered, safe).
  i32x2* pairs = (i32x2*)h0;

  k_detect<<<1, 64, 0, stream>>>(Wp, ei, flags);

  hipMemsetAsync(cnt, 0, (size_t)N * 4, stream);
  int eb = (E + 255) / 256;
  k_pack<<<eb, 256, 0, stream>>>(ei, E, N, cnt, pairs, flags);
  int sb = (N + 1023) / 1024;
  k_scan1<<<sb, 256, 0, stream>>>(cnt, rowptr, bsum, N);
  k_scan2<<<1, 64, 0, stream>>>(bsum, sb, rowptr, N);
  k_scan3<<<(N + 255) / 256, 256, 0, stream>>>(rowptr, cursor, bsum, N);

  const int NPASS = 8;
  int chunk = (N + NPASS - 1) / NPASS;
  for (int r = 0; r < NPASS; ++r) {
    int lo = r * chunk;
    int hi = lo + chunk < N ? lo + chunk : N;
    k_scatter2<<<eb, 256, 0, stream>>>(pairs, E, lo, hi, cursor, colbuf);
  }

  int pb = (N + 63) / 64;  // 64 nodes per 256-thread block (4 waves)
  k_project<<<pb, 256, 0, stream>>>(xc, xs, Wp, bp, Ws, bs, h0, N, flags);

  int nb4 = (N + 3) / 4;  // 4 waves (nodes) per 256-thread block
  k_layer<<<nb4, 256, 0, stream>>>(h0, rowptr, colbuf, Wl1, bl1, Wr1, h1, N, 0,
                                   nullptr, nullptr, nullptr, flags);
  k_layer<<<nb4, 256, 0, stream>>>(h1, rowptr, colbuf, Wl2, bl2, Wr2, h0, N, 0,
                                   nullptr, nullptr, nullptr, flags);
  k_layer<<<nb4, 256, 0, stream>>>(h0, rowptr, colbuf, Wl3, bl3, Wr3, h1, N, 1,
                                   Wo, bo, d_out, flags);
}

// Round 8
// 721.297 us; speedup vs baseline: 1.1462x; 1.0124x over previous
//
#include <hip/hip_runtime.h>
#include <stdint.h>

// ---------------------------------------------------------------------------
// FakeNewsModel: 3-layer GraphSAGE (mean agg), N=50000, E=1.6M, width 64.
// Round 11: occupancy + launch-count package.
//  - k_project v9: K-split x2 in ONE dispatch (1564 blocks: block = nodeblk
//    x K-half, 7 tiles each). Round-10 counters: 100us, occ 21.5% (grid-
//    capped at 782 blocks = 3.05/CU vs LDS cap 3/CU, tail losses), LDS-pipe
//    ~28us busy. Deeper grid queue -> occ toward 37.5%, half the serial
//    chain per block. Partials (no bias) -> h0/h1; k_combine streams
//    h0 = h0+h1+bias (38MB ~ 6us).
//  - scatter: NPASS 8 -> 4 (window 1.6MB still L2-resident).
//  - k_layer: gather unrolled 16-deep (16 loads in flight).
//   k_detect  -> flags[0]=floats-are-bf16?, flags[1]=ints-are-int64?
//   CSR build -> memset(cnt), k_pack, k_scan1/2/3, k_scatter2 x4
//   k_project -> partials; k_combine -> x0 = concat(xc@Wp+bp, xs@Ws+bs)
//   k_layer x3 -> relu(mean-agg@Wl + bl + x@Wr); layer 3 fuses [64,2] head.
// ---------------------------------------------------------------------------

typedef __attribute__((ext_vector_type(8))) unsigned short u16x8;
typedef __attribute__((ext_vector_type(4))) float f32x4;
typedef __attribute__((ext_vector_type(4))) unsigned int u32x4;
typedef __attribute__((ext_vector_type(2))) int i32x2;

static __device__ __forceinline__ float bf2f(unsigned short u) {
  union { unsigned int i; float f; } v;
  v.i = ((unsigned int)u) << 16;
  return v.f;
}

static __device__ __forceinline__ unsigned short f2bf(float f) {
  union { float f; unsigned int i; } v;
  v.f = f;
  unsigned int u = v.i;
  unsigned int r = (u + 0x7FFFu + ((u >> 16) & 1u)) >> 16;  // RNE
  return (unsigned short)r;
}

template <bool BF>
static __device__ __forceinline__ float ldf(const void* p, long long i) {
  if (BF) return bf2f(((const unsigned short*)p)[i]);
  return ((const float*)p)[i];
}

static __device__ __forceinline__ int clampN(int v, int N) {
  return v < 0 ? 0 : (v >= N ? N - 1 : v);
}

// ---------------- dtype detection ----------------
__global__ void k_detect(const void* Wp, const int* ei, int* flags) {
  if (threadIdx.x == 0 && blockIdx.x == 0) {
    const unsigned short* w = (const unsigned short*)Wp;
    int bf = 1;
    for (int i = 0; i < 64; ++i) {
      float v = fabsf(bf2f(w[i]));
      if (!(v < 1.0f)) bf = 0;  // catches NaN too
    }
    flags[0] = bf;
    int i64 = 1;
    for (int i = 0; i < 32; ++i)
      if (ei[2 * i + 1] != 0) i64 = 0;
    flags[1] = i64;
  }
}

static __device__ __forceinline__ int edge_src(const int* ei, int e, int E,
                                               int i64) {
  return i64 ? ei[2 * (long long)e] : ei[e];
}
static __device__ __forceinline__ int edge_dst(const int* ei, int e, int E,
                                               int i64) {
  return i64 ? ei[2 * ((long long)E + e)] : ei[(long long)E + e];
}

// ---------------- CSR build ----------------

// pack (src,dst) into a compact coalesced stream + count degrees.
__global__ __launch_bounds__(256) void k_pack(const int* __restrict__ ei, int E,
                                              int N, int* __restrict__ cnt,
                                              i32x2* __restrict__ pairs,
                                              const int* __restrict__ flags) {
  int e = blockIdx.x * 256 + threadIdx.x;
  if (e < E) {
    int i64 = flags[1];
    int s = clampN(edge_src(ei, e, E, i64), N);
    int d = clampN(edge_dst(ei, e, E, i64), N);
    i32x2 p;
    p[0] = s;
    p[1] = d;
    pairs[e] = p;
    atomicAdd(&cnt[d], 1);
  }
}

__global__ __launch_bounds__(256) void k_scan1(const int* __restrict__ cnt,
                                               int* __restrict__ rowptr,
                                               int* __restrict__ bsum, int N) {
  __shared__ int sh[256];
  int t = threadIdx.x;
  int base = blockIdx.x * 1024 + t * 4;
  int v0 = 0, v1 = 0, v2 = 0, v3 = 0;
  if (base + 0 < N) v0 = cnt[base + 0];
  if (base + 1 < N) v1 = cnt[base + 1];
  if (base + 2 < N) v2 = cnt[base + 2];
  if (base + 3 < N) v3 = cnt[base + 3];
  int s = v0 + v1 + v2 + v3;
  sh[t] = s;
  __syncthreads();
  int acc = s;
  for (int off = 1; off < 256; off <<= 1) {
    int x = 0;
    if (t >= off) x = sh[t - off];
    __syncthreads();
    acc += x;
    sh[t] = acc;
    __syncthreads();
  }
  int run = acc - s;
  if (base + 0 < N) rowptr[base + 0] = run;
  run += v0;
  if (base + 1 < N) rowptr[base + 1] = run;
  run += v1;
  if (base + 2 < N) rowptr[base + 2] = run;
  run += v2;
  if (base + 3 < N) rowptr[base + 3] = run;
  run += v3;
  if (t == 255) bsum[blockIdx.x] = acc;
}

__global__ void k_scan2(int* __restrict__ bsum, int nb,
                        int* __restrict__ rowptr, int N) {
  if (threadIdx.x == 0 && blockIdx.x == 0) {
    int run = 0;
    for (int i = 0; i < nb; ++i) {
      int v = bsum[i];
      bsum[i] = run;
      run += v;
    }
    rowptr[N] = run;
  }
}

__global__ __launch_bounds__(256) void k_scan3(int* __restrict__ rowptr,
                                               int* __restrict__ cursor,
                                               const int* __restrict__ bsum,
                                               int N) {
  int i = blockIdx.x * 256 + threadIdx.x;
  if (i < N) {
    int v = rowptr[i] + bsum[i >> 10];
    rowptr[i] = v;
    cursor[i] = v;
  }
}

// one dst-range pass: only edges with dst in [lo,hi) write. The pass's
// colbuf write window (~E/4*4B ~ 1.6MB) stays L2-resident -> line packing.
__global__ __launch_bounds__(256) void k_scatter2(
    const i32x2* __restrict__ pairs, int E, int lo, int hi,
    int* __restrict__ cursor, int* __restrict__ colbuf) {
  int e = blockIdx.x * 256 + threadIdx.x;
  if (e < E) {
    i32x2 p2 = pairs[e];
    int d = p2[1];
    if (d >= lo && d < hi) {
      int p = atomicAdd(&cursor[d], 1);
      if (p >= 0 && p < E) colbuf[p] = p2[0];
    }
  }
}

// ---------------- projection (v9: K-split x2, W-in-LDS) ---------------------
// Grid = 2 * ceil(N/64) blocks; block b -> nodeblk = b>>1, half = b&1.
// Each block runs 7 of the 14 K-tiles (half 0: tiles 0..6, half 1: 7..13;
// tiles 0..11 = content K=768, 12..13 = style K=128) and writes a bias-free
// partial [64 nodes x 64 cols] to pout (h0 for half 0, h1 for half 1).
// Per tile BOTH x (64x64 f32, stride 68) and W (packed bf16 dwords / f32)
// are double-buffered in LDS; loads issued at phase top, LDS writes after
// compute (T14). Wave w owns cols [8w,8w+8); W read via wave-uniform
// ds_read_b128 + unpack at use. k_combine sums halves + bias.
template <bool BF>
static __device__ void project_body(const void* __restrict__ xc,
                                    const void* __restrict__ xs,
                                    const void* __restrict__ Wp,
                                    const void* __restrict__ Ws,
                                    float* __restrict__ pout, int N,
                                    int nb0, int tile_lo, int tile_hi,
                                    float* __restrict__ lds) {
  float* xt = lds;                                          // [2][64][68] f32
  unsigned int* wtb = (unsigned int*)(lds + 2 * 64 * 68);   // BF: [2][64][16]
  float* wtf = lds + 2 * 64 * 68;                           // f32: [2][64][32]

  int tid = (int)threadIdx.x;
  int w = __builtin_amdgcn_readfirstlane(tid >> 6);  // 0..3 col-octant
  int lane = tid & 63;
  int node = nb0 * 64 + lane;

  int sn = tid >> 2;  // staging row 0..63
  int sj = tid & 3;   // staging quad 0..3
  int gsn = nb0 * 64 + sn;
  int gsnc = gsn < N ? gsn : (N - 1);

  float c[8], s[8];
#pragma unroll
  for (int r = 0; r < 8; ++r) {
    c[r] = 0.f;
    s[r] = 0.f;
  }

  // staging registers (loads land here early; LDS writes happen late)
  u16x8 pr0 = {}, pr1 = {};
  f32x4 pf0 = {}, pf1 = {}, pf2 = {}, pf3 = {};
  u32x4 wrg = {};
  f32x4 wf0 = {}, wf1 = {};

  auto stage_load = [&](int t) {
    // x chunk: 16 elems of node sn's tile-t slice
    long long idx;
    const void* src;
    if (t < 12) {
      src = xc;
      idx = (long long)gsnc * 768 + t * 64 + 16 * sj;
    } else {
      src = xs;
      idx = (long long)gsnc * 128 + (t - 12) * 64 + 16 * sj;
    }
    if (BF) {
      const unsigned short* p = (const unsigned short*)src + idx;
      pr0 = *(const u16x8*)p;
      pr1 = *(const u16x8*)(p + 8);
    } else {
      const float* p = (const float*)src + idx;
      pf0 = *(const f32x4*)(p + 0);
      pf1 = *(const f32x4*)(p + 4);
      pf2 = *(const f32x4*)(p + 8);
      pf3 = *(const f32x4*)(p + 12);
    }
    // W chunk: row sn of tile t, dword-quad sj (verbatim copy)
    int rowg = (t < 12) ? (t * 64 + sn) : ((t - 12) * 64 + sn);
    const void* wsrc = (t < 12) ? Wp : Ws;
    if (BF) {
      wrg = *(const u32x4*)((const unsigned int*)wsrc +
                            (long long)rowg * 16 + 4 * sj);
    } else {
      const float* p = (const float*)wsrc + (long long)rowg * 32 + 8 * sj;
      wf0 = *(const f32x4*)p;
      wf1 = *(const f32x4*)(p + 4);
    }
  };

  auto stage_write = [&](int t) {
    float* row = xt + (t & 1) * (64 * 68) + sn * 68 + 16 * sj;
    if (BF) {
      f32x4 v;
#pragma unroll
      for (int i = 0; i < 4; ++i) v[i] = bf2f(pr0[i]);
      *(f32x4*)(row + 0) = v;
#pragma unroll
      for (int i = 0; i < 4; ++i) v[i] = bf2f(pr0[4 + i]);
      *(f32x4*)(row + 4) = v;
#pragma unroll
      for (int i = 0; i < 4; ++i) v[i] = bf2f(pr1[i]);
      *(f32x4*)(row + 8) = v;
#pragma unroll
      for (int i = 0; i < 4; ++i) v[i] = bf2f(pr1[4 + i]);
      *(f32x4*)(row + 12) = v;
    } else {
      *(f32x4*)(row + 0) = pf0;
      *(f32x4*)(row + 4) = pf1;
      *(f32x4*)(row + 8) = pf2;
      *(f32x4*)(row + 12) = pf3;
    }
    if (BF) {
      *(u32x4*)(wtb + (t & 1) * (64 * 16) + sn * 16 + 4 * sj) = wrg;
    } else {
      float* wrow = wtf + (t & 1) * (64 * 32) + sn * 32 + 8 * sj;
      *(f32x4*)wrow = wf0;
      *(f32x4*)(wrow + 4) = wf1;
    }
  };

  // prologue: stage first tile of this half
  stage_load(tile_lo);
  stage_write(tile_lo);
  __syncthreads();

#pragma unroll 1
  for (int t = tile_lo; t < tile_hi; ++t) {
    if (t + 1 < tile_hi) stage_load(t + 1);  // issue global loads early (T14)

    const float* xrow = xt + (t & 1) * (64 * 68) + lane * 68;
    if (BF) {
      const unsigned int* wbase = wtb + (t & 1) * (64 * 16) + 4 * w;
      if (t < 12) {
#pragma unroll 2
        for (int k0 = 0; k0 < 64; k0 += 4) {
          f32x4 x4 = *(const f32x4*)(xrow + k0);
#pragma unroll
          for (int kk = 0; kk < 4; ++kk) {
            u32x4 wp4 = *(const u32x4*)(wbase + (k0 + kk) * 16);  // uniform
#pragma unroll
            for (int p = 0; p < 4; ++p) {
              union { unsigned int i; float f; } lo, hi;
              lo.i = wp4[p] << 16;
              hi.i = wp4[p] & 0xFFFF0000u;
              c[2 * p + 0] += x4[kk] * lo.f;
              c[2 * p + 1] += x4[kk] * hi.f;
            }
          }
        }
      } else {
#pragma unroll 2
        for (int k0 = 0; k0 < 64; k0 += 4) {
          f32x4 x4 = *(const f32x4*)(xrow + k0);
#pragma unroll
          for (int kk = 0; kk < 4; ++kk) {
            u32x4 wp4 = *(const u32x4*)(wbase + (k0 + kk) * 16);  // uniform
#pragma unroll
            for (int p = 0; p < 4; ++p) {
              union { unsigned int i; float f; } lo, hi;
              lo.i = wp4[p] << 16;
              hi.i = wp4[p] & 0xFFFF0000u;
              s[2 * p + 0] += x4[kk] * lo.f;
              s[2 * p + 1] += x4[kk] * hi.f;
            }
          }
        }
      }
    } else {
      const float* wbase = wtf + (t & 1) * (64 * 32) + 8 * w;
      if (t < 12) {
#pragma unroll 2
        for (int k0 = 0; k0 < 64; k0 += 4) {
          f32x4 x4 = *(const f32x4*)(xrow + k0);
#pragma unroll
          for (int kk = 0; kk < 4; ++kk) {
            const float* wr = wbase + (k0 + kk) * 32;
            f32x4 wa = *(const f32x4*)wr;           // uniform
            f32x4 wb = *(const f32x4*)(wr + 4);     // uniform
#pragma unroll
            for (int r = 0; r < 4; ++r) {
              c[r] += x4[kk] * wa[r];
              c[4 + r] += x4[kk] * wb[r];
            }
          }
        }
      } else {
#pragma unroll 2
        for (int k0 = 0; k0 < 64; k0 += 4) {
          f32x4 x4 = *(const f32x4*)(xrow + k0);
#pragma unroll
          for (int kk = 0; kk < 4; ++kk) {
            const float* wr = wbase + (k0 + kk) * 32;
            f32x4 wa = *(const f32x4*)wr;
            f32x4 wb = *(const f32x4*)(wr + 4);
#pragma unroll
            for (int r = 0; r < 4; ++r) {
              s[r] += x4[kk] * wa[r];
              s[4 + r] += x4[kk] * wb[r];
            }
          }
        }
      }
    }

    if (t + 1 < tile_hi) stage_write(t + 1);  // LDS writes late
    __syncthreads();
  }

  if (node < N) {
    float* orow = pout + (long long)node * 64;
    f32x4 v;
#pragma unroll
    for (int r = 0; r < 4; ++r) v[r] = c[r];
    *(f32x4*)(orow + 8 * w) = v;
#pragma unroll
    for (int r = 0; r < 4; ++r) v[r] = c[4 + r];
    *(f32x4*)(orow + 8 * w + 4) = v;
#pragma unroll
    for (int r = 0; r < 4; ++r) v[r] = s[r];
    *(f32x4*)(orow + 32 + 8 * w) = v;
#pragma unroll
    for (int r = 0; r < 4; ++r) v[r] = s[4 + r];
    *(f32x4*)(orow + 32 + 8 * w + 4) = v;
  }
}

__global__ __launch_bounds__(256) void k_project(
    const void* __restrict__ xc, const void* __restrict__ xs,
    const void* __restrict__ Wp, const void* __restrict__ Ws,
    float* __restrict__ p0, float* __restrict__ p1, int N,
    const int* __restrict__ flags) {
  __shared__ float lds[2 * 64 * 68 + 2 * 64 * 32];  // 51200 B
  int b = (int)blockIdx.x;
  int nb0 = b >> 1;
  int half = b & 1;
  float* pout = half ? p1 : p0;
  int tlo = half * 7, thi = half * 7 + 7;
  if (flags[0])
    project_body<true>(xc, xs, Wp, Ws, pout, N, nb0, tlo, thi, lds);
  else
    project_body<false>(xc, xs, Wp, Ws, pout, N, nb0, tlo, thi, lds);
}

// combine the two K-half partials + bias: h0 = p0 + p1 + bias
template <bool BF>
static __device__ void combine_body(float* __restrict__ p0,
                                    const float* __restrict__ p1,
                                    const void* __restrict__ bp,
                                    const void* __restrict__ bs, int N) {
  long long i = (long long)blockIdx.x * 256 + threadIdx.x;  // f32x4 index
  long long tot = (long long)N * 16;
  if (i < tot) {
    int oc = (int)((i & 15) * 4);  // col 0,4,...,60
    f32x4 a = *(f32x4*)(p0 + i * 4);
    f32x4 b = *(const f32x4*)(p1 + i * 4);
    f32x4 v;
#pragma unroll
    for (int r = 0; r < 4; ++r) {
      int col = oc + r;
      float bias = (col < 32) ? ldf<BF>(bp, col) : ldf<BF>(bs, col - 32);
      v[r] = a[r] + b[r] + bias;
    }
    *(f32x4*)(p0 + i * 4) = v;
  }
}

__global__ __launch_bounds__(256) void k_combine(
    float* __restrict__ p0, const float* __restrict__ p1,
    const void* __restrict__ bp, const void* __restrict__ bs, int N,
    const int* __restrict__ flags) {
  if (flags[0])
    combine_body<true>(p0, p1, bp, bs, N);
  else
    combine_body<false>(p0, p1, bp, bs, N);
}

// ---------------- SAGE layer ----------------
template <bool BF>
static __device__ void layer_body(const float* __restrict__ hin,
                                  const int* __restrict__ rowptr,
                                  const int* __restrict__ colbuf,
                                  const void* Wl, const void* bl,
                                  const void* Wr, float* __restrict__ hout,
                                  int N, int last, const void* Wo,
                                  const void* bo, void* outp) {
  int node = (int)((blockIdx.x * blockDim.x + threadIdx.x) >> 6);
  int lane = (int)(threadIdx.x & 63);
  if (node >= N) return;
  int rs = rowptr[node], re = rowptr[node + 1];
  float xself = hin[(long long)node * 64 + lane];
  float agg0 = 0.f, agg1 = 0.f, agg2 = 0.f, agg3 = 0.f;
  float agg4 = 0.f, agg5 = 0.f, agg6 = 0.f, agg7 = 0.f;
  for (int cb = rs; cb < re; cb += 64) {
    int sidx = 0;
    if (cb + lane < re) sidx = clampN(colbuf[cb + lane], N);
    int c = re - cb;
    if (c > 64) c = 64;
    int t = 0;
    // 16 independent loads in flight (L3-latency hiding)
    for (; t + 16 <= c; t += 16) {
      int s0 = __builtin_amdgcn_readlane(sidx, t + 0);
      int s1 = __builtin_amdgcn_readlane(sidx, t + 1);
      int s2 = __builtin_amdgcn_readlane(sidx, t + 2);
      int s3 = __builtin_amdgcn_readlane(sidx, t + 3);
      int s4 = __builtin_amdgcn_readlane(sidx, t + 4);
      int s5 = __builtin_amdgcn_readlane(sidx, t + 5);
      int s6 = __builtin_amdgcn_readlane(sidx, t + 6);
      int s7 = __builtin_amdgcn_readlane(sidx, t + 7);
      int s8 = __builtin_amdgcn_readlane(sidx, t + 8);
      int s9 = __builtin_amdgcn_readlane(sidx, t + 9);
      int sa = __builtin_amdgcn_readlane(sidx, t + 10);
      int sb = __builtin_amdgcn_readlane(sidx, t + 11);
      int sc = __builtin_amdgcn_readlane(sidx, t + 12);
      int sd = __builtin_amdgcn_readlane(sidx, t + 13);
      int se = __builtin_amdgcn_readlane(sidx, t + 14);
      int sf = __builtin_amdgcn_readlane(sidx, t + 15);
      float v0 = hin[(long long)s0 * 64 + lane];
      float v1 = hin[(long long)s1 * 64 + lane];
      float v2 = hin[(long long)s2 * 64 + lane];
      float v3 = hin[(long long)s3 * 64 + lane];
      float v4 = hin[(long long)s4 * 64 + lane];
      float v5 = hin[(long long)s5 * 64 + lane];
      float v6 = hin[(long long)s6 * 64 + lane];
      float v7 = hin[(long long)s7 * 64 + lane];
      float v8 = hin[(long long)s8 * 64 + lane];
      float v9 = hin[(long long)s9 * 64 + lane];
      float va = hin[(long long)sa * 64 + lane];
      float vb = hin[(long long)sb * 64 + lane];
      float vc = hin[(long long)sc * 64 + lane];
      float vd = hin[(long long)sd * 64 + lane];
      float ve = hin[(long long)se * 64 + lane];
      float vf = hin[(long long)sf * 64 + lane];
      agg0 += v0 + v8;
      agg1 += v1 + v9;
      agg2 += v2 + va;
      agg3 += v3 + vb;
      agg4 += v4 + vc;
      agg5 += v5 + vd;
      agg6 += v6 + ve;
      agg7 += v7 + vf;
    }
    for (; t + 8 <= c; t += 8) {
      int s0 = __builtin_amdgcn_readlane(sidx, t + 0);
      int s1 = __builtin_amdgcn_readlane(sidx, t + 1);
      int s2 = __builtin_amdgcn_readlane(sidx, t + 2);
      int s3 = __builtin_amdgcn_readlane(sidx, t + 3);
      int s4 = __builtin_amdgcn_readlane(sidx, t + 4);
      int s5 = __builtin_amdgcn_readlane(sidx, t + 5);
      int s6 = __builtin_amdgcn_readlane(sidx, t + 6);
      int s7 = __builtin_amdgcn_readlane(sidx, t + 7);
      float v0 = hin[(long long)s0 * 64 + lane];
      float v1 = hin[(long long)s1 * 64 + lane];
      float v2 = hin[(long long)s2 * 64 + lane];
      float v3 = hin[(long long)s3 * 64 + lane];
      float v4 = hin[(long long)s4 * 64 + lane];
      float v5 = hin[(long long)s5 * 64 + lane];
      float v6 = hin[(long long)s6 * 64 + lane];
      float v7 = hin[(long long)s7 * 64 + lane];
      agg0 += v0;
      agg1 += v1;
      agg2 += v2;
      agg3 += v3;
      agg4 += v4;
      agg5 += v5;
      agg6 += v6;
      agg7 += v7;
    }
    for (; t < c; ++t) {
      int s = __builtin_amdgcn_readlane(sidx, t);
      agg0 += hin[(long long)s * 64 + lane];
    }
  }
  float agg = ((agg0 + agg1) + (agg2 + agg3)) + ((agg4 + agg5) + (agg6 + agg7));
  int deg = re - rs;
  if (deg > 0) agg *= (1.f / (float)deg);

  float o = ldf<BF>(bl, lane);
#pragma unroll 8
  for (int d = 0; d < 64; ++d) {
    float ad = __uint_as_float(
        __builtin_amdgcn_readlane(__float_as_uint(agg), d));
    float xd = __uint_as_float(
        __builtin_amdgcn_readlane(__float_as_uint(xself), d));
    o += ad * ldf<BF>(Wl, d * 64 + lane);
    o += xd * ldf<BF>(Wr, d * 64 + lane);
  }
  o = fmaxf(o, 0.f);

  if (!last) {
    hout[(long long)node * 64 + lane] = o;
  } else {
    float c0 = o * ldf<BF>(Wo, lane * 2 + 0);
    float c1 = o * ldf<BF>(Wo, lane * 2 + 1);
    for (int off = 32; off > 0; off >>= 1) {
      c0 += __shfl_xor(c0, off, 64);
      c1 += __shfl_xor(c1, off, 64);
    }
    if (lane == 0) {
      float r0 = c0 + ldf<BF>(bo, 0);
      float r1 = c1 + ldf<BF>(bo, 1);
      if (BF) {
        unsigned short* o16 = (unsigned short*)outp;
        o16[(long long)node * 2 + 0] = f2bf(r0);
        o16[(long long)node * 2 + 1] = f2bf(r1);
      } else {
        float* o32 = (float*)outp;
        o32[(long long)node * 2 + 0] = r0;
        o32[(long long)node * 2 + 1] = r1;
      }
    }
  }
}

__global__ __launch_bounds__(256) void k_layer(
    const float* hin, const int* rowptr, const int* colbuf, const void* Wl,
    const void* bl, const void* Wr, float* hout, int N, int last,
    const void* Wo, const void* bo, void* outp, const int* __restrict__ flags) {
  if (flags[0])
    layer_body<true>(hin, rowptr, colbuf, Wl, bl, Wr, hout, N, last, Wo, bo,
                     outp);
  else
    layer_body<false>(hin, rowptr, colbuf, Wl, bl, Wr, hout, N, last, Wo, bo,
                      outp);
}

// ---------------- host ----------------

extern "C" void kernel_launch(void* const* d_in, const int* in_sizes, int n_in,
                              void* d_out, int out_size, void* d_ws,
                              size_t ws_size, hipStream_t stream) {
  const void* xc = d_in[0];
  const void* xs = d_in[1];
  const int* ei = (const int*)d_in[2];
  const void* Wp = d_in[4];
  const void* bp = d_in[5];
  const void* Ws = d_in[6];
  const void* bs = d_in[7];
  const void* Wl1 = d_in[8];
  const void* bl1 = d_in[9];
  const void* Wr1 = d_in[10];
  const void* Wl2 = d_in[11];
  const void* bl2 = d_in[12];
  const void* Wr2 = d_in[13];
  const void* Wl3 = d_in[14];
  const void* bl3 = d_in[15];
  const void* Wr3 = d_in[16];
  const void* Wo = d_in[17];
  const void* bo = d_in[18];

  int N = out_size / 2;   // output is [N, 2]
  int E = in_sizes[3];    // edge_type has E elements

  char* ws = (char*)d_ws;
  size_t off = 0;
  auto alloc = [&](size_t bytes) {
    char* p = ws + off;
    off += (bytes + 255) & ~(size_t)255;
    return p;
  };
  int* colbuf = (int*)alloc((size_t)E * 4);
  int* cnt = (int*)alloc((size_t)N * 4);
  int* rowptr = (int*)alloc((size_t)(N + 1) * 4);
  int* cursor = (int*)alloc((size_t)N * 4);
  int* bsum = (int*)alloc(4096);
  int* flags = (int*)alloc(256);
  float* h0 = (float*)alloc((size_t)N * 64 * 4);
  float* h1 = (float*)alloc((size_t)N * 64 * 4);
  (void)ws_size;
  (void)n_in;

  // pairs (E * 8B) aliases h0 (N*64*4B = 12.8MB >= E*8B = 12.8MB):
  // written by k_pack, consumed by the scatter passes, then h0 is
  // overwritten by k_project (stream-ordered, safe).
  i32x2* pairs = (i32x2*)h0;

  k_detect<<<1, 64, 0, stream>>>(Wp, ei, flags);

  hipMemsetAsync(cnt, 0, (size_t)N * 4, stream);
  int eb = (E + 255) / 256;
  k_pack<<<eb, 256, 0, stream>>>(ei, E, N, cnt, pairs, flags);
  int sb = (N + 1023) / 1024;
  k_scan1<<<sb, 256, 0, stream>>>(cnt, rowptr, bsum, N);
  k_scan2<<<1, 64, 0, stream>>>(bsum, sb, rowptr, N);
  k_scan3<<<(N + 255) / 256, 256, 0, stream>>>(rowptr, cursor, bsum, N);

  const int NPASS = 4;
  int chunk = (N + NPASS - 1) / NPASS;
  for (int r = 0; r < NPASS; ++r) {
    int lo = r * chunk;
    int hi = lo + chunk < N ? lo + chunk : N;
    k_scatter2<<<eb, 256, 0, stream>>>(pairs, E, lo, hi, cursor, colbuf);
  }

  // K-split projection: 2 blocks per 64-node group (halves of K), then
  // combine partials + bias into h0.
  int pb = (N + 63) / 64;
  k_project<<<2 * pb, 256, 0, stream>>>(xc, xs, Wp, Ws, h0, h1, N, flags);
  int cb = (int)(((long long)N * 16 + 255) / 256);
  k_combine<<<cb, 256, 0, stream>>>(h0, h1, bp, bs, N, flags);

  int nb4 = (N + 3) / 4;  // 4 waves (nodes) per 256-thread block
  k_layer<<<nb4, 256, 0, stream>>>(h0, rowptr, colbuf, Wl1, bl1, Wr1, h1, N, 0,
                                   nullptr, nullptr, nullptr, flags);
  k_layer<<<nb4, 256, 0, stream>>>(h1, rowptr, colbuf, Wl2, bl2, Wr2, h0, N, 0,
                                   nullptr, nullptr, nullptr, flags);
  k_layer<<<nb4, 256, 0, stream>>>(h0, rowptr, colbuf, Wl3, bl3, Wr3, h1, N, 1,
                                   Wo, bo, d_out, flags);
}